// Round 13
// baseline (278.430 us; speedup 1.0000x reference)
//
#include <hip/hip_runtime.h>
#include <hip/hip_bf16.h>

#define D_MODEL 1024
#define NH 16
#define HD 64
#define SEQ 2048
#define NB 2
#define LOG2E 1.4426950408889634f

typedef __attribute__((ext_vector_type(8))) short sh8;
typedef __attribute__((ext_vector_type(4))) short sh4;
typedef __attribute__((ext_vector_type(4))) float fx4;

__device__ __forceinline__ short f2bf(float x) {
    union { float f; unsigned u; } v; v.f = x;
    unsigned r = (v.u + 0x7FFFu + ((v.u >> 16) & 1u)) >> 16;
    return (short)r;
}
__device__ __forceinline__ float bf2f(short b) {
    union { float f; unsigned u; } v; v.u = ((unsigned)(unsigned short)b) << 16;
    return v.f;
}
__device__ __forceinline__ short truncbf(float x) {
    union { float f; unsigned u; } v; v.f = x;
    return (short)(v.u >> 16);
}

// async global->LDS, 16B per lane. LDS dest linear: wave base + lane*16.
__device__ __forceinline__ void gl_lds16(const short* g, short* l) {
    __builtin_amdgcn_global_load_lds(
        (const __attribute__((address_space(1))) void*)(uintptr_t)(const void*)g,
        (__attribute__((address_space(3))) void*)(uintptr_t)(void*)l, 16, 0, 0);
}

// ---------------- bias table: bt[h][delta+2047] = (bias - 40) * log2(e) ------
__global__ __launch_bounds__(256) void bias_kernel(const float* __restrict__ rel_emb,
                                                   float* __restrict__ bt) {
    int i = blockIdx.x * 256 + threadIdx.x;
    if (i >= NH * 4095) return;
    int h = i / 4095;
    int delta = (i % 4095) - 2047;
    int rb = delta > 0 ? 16 : 0;
    int ad = delta < 0 ? -delta : delta;
    int bidx;
    if (ad < 8) bidx = ad;
    else if (ad < 12) bidx = 8;
    else if (ad < 16) bidx = 9;
    else if (ad < 23) bidx = 10;
    else if (ad < 32) bidx = 11;
    else if (ad < 46) bidx = 12;
    else if (ad < 64) bidx = 13;
    else if (ad < 91) bidx = 14;
    else bidx = 15;
    bt[h * 4095 + (delta + 2047)] = (rel_emb[(rb + bidx) * NH + h] - 40.0f) * LOG2E;
}

// ---------------- presplit hidden: fp32 -> (hi, lo) bf16 ----------------------
__global__ __launch_bounds__(256) void presplit_kernel(const float* __restrict__ src,
                                                       short* __restrict__ hi,
                                                       short* __restrict__ lo, int n4) {
    int idx = blockIdx.x * 256 + threadIdx.x;
    if (idx >= n4) return;
    float4 v = ((const float4*)src)[idx];
    const float* p = (const float*)&v;
    sh4 h, l;
#pragma unroll
    for (int j = 0; j < 4; ++j) {
        short hh = f2bf(p[j]);
        h[j] = hh;
        l[j] = f2bf(p[j] - bf2f(hh));
    }
    *(sh4*)&hi[(size_t)idx * 4] = h;
    *(sh4*)&lo[(size_t)idx * 4] = l;
}

// ---------------- fused weight presplit: Wq/Wk/Wv hi+lo, Wo hi ----------------
__global__ __launch_bounds__(256) void presplitW_kernel(
    const float* __restrict__ Wq, const float* __restrict__ Wk,
    const float* __restrict__ Wv, const float* __restrict__ Wo,
    short* __restrict__ Wqh, short* __restrict__ Wql,
    short* __restrict__ Wkh, short* __restrict__ Wkl,
    short* __restrict__ Wvh, short* __restrict__ Wvl,
    short* __restrict__ Woh) {
    int idx = blockIdx.x * 256 + threadIdx.x;   // 4 x 262144
    int sel = idx >> 18;
    int loc = idx & 0x3FFFF;
    const float* src = sel == 0 ? Wq : (sel == 1 ? Wk : (sel == 2 ? Wv : Wo));
    float4 v = ((const float4*)src)[loc];
    const float* p = (const float*)&v;
    sh4 h, l;
#pragma unroll
    for (int j = 0; j < 4; ++j) {
        short hh = f2bf(p[j]);
        h[j] = hh;
        l[j] = f2bf(p[j] - bf2f(hh));
    }
    if (sel == 3) {
        *(sh4*)&Woh[(size_t)loc * 4] = h;
    } else {
        short* hi = sel == 0 ? Wqh : (sel == 1 ? Wkh : Wvh);
        short* lo = sel == 0 ? Wql : (sel == 1 ? Wkl : Wvl);
        *(sh4*)&hi[(size_t)loc * 4] = h;
        *(sh4*)&lo[(size_t)loc * 4] = l;
    }
}

// ---------------- QKV GEMM v7: Q/K bf16x3, V single-pass (bf16 output) -------
__global__ __launch_bounds__(256, 3) void qkv_gemm(
    const short* __restrict__ Hh, const short* __restrict__ Hl,
    const short* __restrict__ Wqh, const short* __restrict__ Wql,
    const short* __restrict__ Wkh, const short* __restrict__ Wkl,
    const short* __restrict__ Wvh, const short* __restrict__ Wvl,
    short* __restrict__ Qh, short* __restrict__ Ql,
    short* __restrict__ Kh, short* __restrict__ Kl, short* __restrict__ Vt) {
    __shared__ short Ah[4096];
    __shared__ short Al[4096];
    __shared__ short Bh[4096];
    __shared__ short Bl[4096];

    int t = threadIdx.x;
    int lane = t & 63, w = t >> 6;
    int wr = w >> 1, wc = w & 1;
    int fr = lane & 15, g = lane >> 4;
    int qrhi = g << 2;

    int lin = blockIdx.y * 24 + blockIdx.x;
    int xcd = lin & 7, i5 = lin >> 3;
    int nb = xcd * 3 + i5 % 3;
    int mb = i5 / 3;

    int proj = (nb * 128) >> 10;
    int nlocal = (nb * 128) & 1023;
    const short* Wh = proj == 0 ? Wqh : (proj == 1 ? Wkh : Wvh);
    const short* Wl = proj == 0 ? Wql : (proj == 1 ? Wkl : Wvl);

    const short* Ahb = Hh + (size_t)(mb * 128) * D_MODEL;
    const short* Alb = Hl + (size_t)(mb * 128) * D_MODEL;
    const short* Bhb = Wh + (size_t)nlocal * D_MODEL;
    const short* Blb = Wl + (size_t)nlocal * D_MODEL;

    fx4 acc[4][4];
#pragma unroll
    for (int i = 0; i < 4; ++i)
#pragma unroll
        for (int j = 0; j < 4; ++j) acc[i][j] = (fx4){0.f, 0.f, 0.f, 0.f};

    auto stage = [&](int kt) {
        int kb = kt * 32;
#pragma unroll
        for (int i = 0; i < 2; ++i) {
            int idx = i * 256 + t;
            int row = idx >> 2;
            int csw = ((idx & 3) ^ (row & 3)) << 3;
            size_t go = (size_t)row * D_MODEL + kb + csw;
            int dst = (i * 256 + w * 64) * 8;
            gl_lds16(Ahb + go, &Ah[dst]);
            gl_lds16(Bhb + go, &Bh[dst]);
            if (proj != 2) {        // V: single-pass, no lo staging
                gl_lds16(Alb + go, &Al[dst]);
                gl_lds16(Blb + go, &Bl[dst]);
            }
        }
    };
    auto compute = [&]() {
        sh8 afh[4], bfh[4];
#pragma unroll
        for (int mi = 0; mi < 4; ++mi) {
            int row = wr * 64 + mi * 16 + fr;
            afh[mi] = *(const sh8*)&Ah[row * 32 + ((g ^ (row & 3)) << 3)];
        }
#pragma unroll
        for (int ni = 0; ni < 4; ++ni) {
            int row = wc * 64 + ni * 16 + fr;
            bfh[ni] = *(const sh8*)&Bh[row * 32 + ((g ^ (row & 3)) << 3)];
        }
#pragma unroll
        for (int mi = 0; mi < 4; ++mi)
#pragma unroll
            for (int ni = 0; ni < 4; ++ni)
                acc[mi][ni] = __builtin_amdgcn_mfma_f32_16x16x32_bf16(afh[mi], bfh[ni], acc[mi][ni], 0, 0, 0);
        if (proj != 2) {
            sh8 afl[4], bfl[4];
#pragma unroll
            for (int mi = 0; mi < 4; ++mi) {
                int row = wr * 64 + mi * 16 + fr;
                afl[mi] = *(const sh8*)&Al[row * 32 + ((g ^ (row & 3)) << 3)];
            }
#pragma unroll
            for (int ni = 0; ni < 4; ++ni) {
                int row = wc * 64 + ni * 16 + fr;
                bfl[ni] = *(const sh8*)&Bl[row * 32 + ((g ^ (row & 3)) << 3)];
            }
#pragma unroll
            for (int mi = 0; mi < 4; ++mi)
#pragma unroll
                for (int ni = 0; ni < 4; ++ni)
                    acc[mi][ni] = __builtin_amdgcn_mfma_f32_16x16x32_bf16(afh[mi], bfl[ni], acc[mi][ni], 0, 0, 0);
#pragma unroll
            for (int mi = 0; mi < 4; ++mi)
#pragma unroll
                for (int ni = 0; ni < 4; ++ni)
                    acc[mi][ni] = __builtin_amdgcn_mfma_f32_16x16x32_bf16(afl[mi], bfh[ni], acc[mi][ni], 0, 0, 0);
        }
    };

#pragma unroll 1
    for (int kt = 0; kt < 32; ++kt) {
        __syncthreads();
        stage(kt);
        __syncthreads();
        compute();
    }

#pragma unroll
    for (int mi = 0; mi < 4; ++mi)
#pragma unroll
        for (int ni = 0; ni < 4; ++ni)
#pragma unroll
            for (int r = 0; r < 4; ++r) {
                int m = mb * 128 + wr * 64 + mi * 16 + qrhi + r;
                int n = nb * 128 + wc * 64 + ni * 16 + fr;
                int nn = n & 1023;
                int h = nn >> 6, d = nn & 63;
                int b = m >> 11, s = m & 2047;
                size_t bh = (size_t)(b * NH + h);
                float val = acc[mi][ni][r];
                if (proj == 0) {
                    short hh = f2bf(val);
                    Qh[(bh * SEQ + s) * HD + d] = hh;
                    Ql[(bh * SEQ + s) * HD + d] = f2bf(val - bf2f(hh));
                } else if (proj == 1) {
                    short hh = f2bf(val);
                    Kh[(bh * SEQ + s) * HD + d] = hh;
                    Kl[(bh * SEQ + s) * HD + d] = f2bf(val - bf2f(hh));
                } else {
                    Vt[(bh * HD + d) * SEQ + s] = f2bf(val);
                }
            }
}

// swizzled LDS index (shorts): row-major [64][64], XOR bank swizzle
#define SW(row, scol) (((row) << 6) + ((scol) ^ (((row) & 7) << 3)))

// ---------------- flash attention v8: R11 body at 4 blocks/CU ----------------
__global__ __launch_bounds__(256, 4) void attn_kernel(
    const short* __restrict__ Qhg, const short* __restrict__ Qlg,
    const short* __restrict__ Khg, const short* __restrict__ Klg,
    const short* __restrict__ Vtg, const float* __restrict__ biasS,
    short* __restrict__ poB, float* __restrict__ plB) {
    __shared__ short Ks[64 * 64];
    __shared__ short Kls[64 * 64];
    __shared__ short Vs[64 * 64];
    __shared__ short Pl[4 * 16 * 72];
    __shared__ float Bt[192];

    int t = threadIdx.x;
    int lane = t & 63, w = t >> 6;
    int fr = lane & 15, g = lane >> 4;
    int fk = g << 3;
    int qrhi = g << 2;
    int qt = blockIdx.x, h = blockIdx.y;
    int b = blockIdx.z >> 1, half = blockIdx.z & 1;
    int qbase = qt * 128;
    int ktbase = half * 16;
    size_t bh = (size_t)(b * NH + h);

    sh8 qh[2][2], ql[2][2];
#pragma unroll
    for (int qg = 0; qg < 2; ++qg)
#pragma unroll
        for (int ks = 0; ks < 2; ++ks) {
            int row = qbase + w * 32 + qg * 16 + fr;
            qh[qg][ks] = *(const sh8*)&Qhg[(bh * SEQ + row) * HD + ks * 32 + fk];
            ql[qg][ks] = *(const sh8*)&Qlg[(bh * SEQ + row) * HD + ks * 32 + fk];
        }

    float lrow[2][4];
    fx4 o[2][4];
#pragma unroll
    for (int qg = 0; qg < 2; ++qg) {
#pragma unroll
        for (int r = 0; r < 4; ++r) lrow[qg][r] = 0.f;
#pragma unroll
        for (int di = 0; di < 4; ++di) o[qg][di] = (fx4){0.f, 0.f, 0.f, 0.f};
    }

    // hoisted kt-invariant LDS offsets
    int fo[2][4];
#pragma unroll
    for (int ks = 0; ks < 2; ++ks)
#pragma unroll
        for (int i = 0; i < 4; ++i) fo[ks][i] = SW(i * 16 + fr, ks * 32 + fk);
    int shftw = ((qrhi >> 3) & 1) << 3;
    int shftr = ((fr >> 3) & 1) << 3;
    int pbase = w * 1152;
    int pw = pbase + qrhi * 72 + fr + shftw;
    int pr0 = pbase + fr * 72 + fk + shftr;

    // glds staging: linear dest chunk cd; source chunk = p ^ (row&7)
    int sd[2], srow[2], schunk[2];
#pragma unroll
    for (int i = 0; i < 2; ++i) {
        int cd = i * 256 + t;
        int row = cd >> 3, p = cd & 7;
        sd[i] = cd * 8;
        srow[i] = row;
        schunk[i] = (p ^ (row & 7)) << 3;
    }

    const short* kbase = Khg + bh * SEQ * HD;
    const short* klbase = Klg + bh * SEQ * HD;
    const short* vbase = Vtg + bh * HD * SEQ;

    for (int ktl = 0; ktl < 16; ++ktl) {
        int kt = ktbase + ktl;
        __syncthreads();    // previous iteration's LDS reads complete
#pragma unroll
        for (int i = 0; i < 2; ++i) {
            gl_lds16(kbase + (size_t)(kt * 64 + srow[i]) * HD + schunk[i], &Ks[sd[i]]);
            gl_lds16(klbase + (size_t)(kt * 64 + srow[i]) * HD + schunk[i], &Kls[sd[i]]);
            gl_lds16(vbase + (size_t)srow[i] * SEQ + kt * 64 + schunk[i], &Vs[sd[i]]);
        }
        if (t < 191) Bt[t] = biasS[h * 4095 + 2047 + (kt * 64 - qbase - 127) + t];
        __syncthreads();    // glds + bias landed

        // QK^T (bf16x3)
        fx4 sc[2][4];
#pragma unroll
        for (int qg = 0; qg < 2; ++qg)
#pragma unroll
            for (int ni = 0; ni < 4; ++ni) sc[qg][ni] = (fx4){0.f, 0.f, 0.f, 0.f};
        __builtin_amdgcn_s_setprio(1);
#pragma unroll
        for (int ks = 0; ks < 2; ++ks)
#pragma unroll
            for (int ni = 0; ni < 4; ++ni) {
                sh8 kf = *(const sh8*)&Ks[fo[ks][ni]];
                sh8 klf = *(const sh8*)&Kls[fo[ks][ni]];
#pragma unroll
                for (int qg = 0; qg < 2; ++qg) {
                    sc[qg][ni] = __builtin_amdgcn_mfma_f32_16x16x32_bf16(qh[qg][ks], kf, sc[qg][ni], 0, 0, 0);
                    sc[qg][ni] = __builtin_amdgcn_mfma_f32_16x16x32_bf16(ql[qg][ks], kf, sc[qg][ni], 0, 0, 0);
                    sc[qg][ni] = __builtin_amdgcn_mfma_f32_16x16x32_bf16(qh[qg][ks], klf, sc[qg][ni], 0, 0, 0);
                }
            }
        __builtin_amdgcn_s_setprio(0);

        // per-qg: softmax -> P -> PV
#pragma unroll
        for (int qg = 0; qg < 2; ++qg) {
#pragma unroll
            for (int r = 0; r < 4; ++r) {
                int bidx0 = 127 + fr - (w * 32 + qg * 16 + qrhi + r);
                float psum = 0.f;
#pragma unroll
                for (int ni = 0; ni < 4; ++ni) {
                    float p = exp2f(fmaf(sc[qg][ni][r], LOG2E, Bt[bidx0 + ni * 16]));
                    sc[qg][ni][r] = p;
                    psum += p;
                }
                lrow[qg][r] += psum;
#pragma unroll
                for (int ni = 0; ni < 4; ++ni)
                    Pl[pw + r * 72 + ni * 16] = truncbf(sc[qg][ni][r]);
            }
            sh8 pa0 = *(const sh8*)&Pl[pr0];
            sh8 pa1 = *(const sh8*)&Pl[pr0 + 32];
            __builtin_amdgcn_s_setprio(1);
#pragma unroll
            for (int di = 0; di < 4; ++di) {
                sh8 vb0 = *(const sh8*)&Vs[fo[0][di]];
                sh8 vb1 = *(const sh8*)&Vs[fo[1][di]];
                o[qg][di] = __builtin_amdgcn_mfma_f32_16x16x32_bf16(pa0, vb0, o[qg][di], 0, 0, 0);
                o[qg][di] = __builtin_amdgcn_mfma_f32_16x16x32_bf16(pa1, vb1, o[qg][di], 0, 0, 0);
            }
            __builtin_amdgcn_s_setprio(0);
        }
    }

#pragma unroll
    for (int qg = 0; qg < 2; ++qg)
#pragma unroll
        for (int r = 0; r < 4; ++r) {
#pragma unroll
            for (int off = 1; off < 16; off <<= 1)
                lrow[qg][r] += __shfl_xor(lrow[qg][r], off, 64);
        }

    // epilogue: normalized partial O (bf16) + partial l (f32)
    short* po = poB + (size_t)half * (NB * SEQ * (size_t)D_MODEL);
    float* pl = plB + (size_t)half * (NB * NH * SEQ);
#pragma unroll
    for (int qg = 0; qg < 2; ++qg)
#pragma unroll
        for (int di = 0; di < 4; ++di)
#pragma unroll
            for (int r = 0; r < 4; ++r) {
                int q = qbase + w * 32 + qg * 16 + qrhi + r;
                int d = di * 16 + fr;
                po[((size_t)b * SEQ + q) * D_MODEL + h * HD + d] =
                    f2bf(o[qg][di][r] / lrow[qg][r]);
            }
    if (fr == 0) {
#pragma unroll
        for (int qg = 0; qg < 2; ++qg)
#pragma unroll
            for (int r = 0; r < 4; ++r) {
                int q = qbase + w * 32 + qg * 16 + qrhi + r;
                pl[bh * SEQ + q] = lrow[qg][r];
            }
    }
}

// ---------------- combine: ctx = (l0*O0' + l1*O1') / (l0+l1), bf16 -----------
__global__ __launch_bounds__(256) void combine_kernel(
    const short* __restrict__ poB, const float* __restrict__ plB,
    short* __restrict__ ctx) {
    const size_t NEl = (size_t)NB * SEQ * D_MODEL;
    int idx = blockIdx.x * 256 + threadIdx.x;
    if (idx >= (int)(NEl / 8)) return;
    size_t e = (size_t)idx * 8;
    int c = (int)(e & 1023);
    int h = c >> 6;
    int bq = (int)(e >> 10);
    int b = bq >> 11, q = bq & 2047;
    sh8 a0 = *(const sh8*)&poB[e];
    sh8 a1 = *(const sh8*)&poB[NEl + e];
    int li = (b * NH + h) * SEQ + q;
    float l0 = plB[li];
    float l1 = plB[NB * NH * SEQ + li];
    float inv = 1.0f / (l0 + l1);
    float w0 = l0 * inv, w1 = l1 * inv;
    sh8 r;
#pragma unroll
    for (int j = 0; j < 8; ++j)
        r[j] = f2bf(bf2f(a0[j]) * w0 + bf2f(a1[j]) * w1);
    *(sh8*)&ctx[e] = r;
}

// ---------------- output projection: 64x128 tile, dbuf, gload_lds ------------
__global__ __launch_bounds__(256) void o_gemm(
    const short* __restrict__ Actx, const short* __restrict__ Woh,
    float* __restrict__ out) {
    __shared__ short Ab[2][2048];
    __shared__ short Bb[2][4096];

    int t = threadIdx.x;
    int lane = t & 63, w = t >> 6;
    int wr = w >> 1, wc = w & 1;
    int fr = lane & 15, g = lane >> 4;
    int qrhi = g << 2;

    int lin = blockIdx.y * 8 + blockIdx.x;      // 512 blocks
    int swz = (lin & 7) * 64 + (lin >> 3);
    int nb = swz & 7, mb = swz >> 3;

    fx4 acc[2][4];
#pragma unroll
    for (int i = 0; i < 2; ++i)
#pragma unroll
        for (int j = 0; j < 4; ++j) acc[i][j] = (fx4){0.f, 0.f, 0.f, 0.f};

    int row0 = t >> 2, c0 = t & 3;

    auto stage = [&](int kt, int buf) {
        int kb = kt * 32;
        {
            int row = row0;
            int csw = (c0 ^ (row & 3)) << 3;
            gl_lds16(&Actx[(size_t)(mb * 64 + row) * D_MODEL + kb + csw],
                     &Ab[buf][(w * 64) * 8]);
        }
#pragma unroll
        for (int i = 0; i < 2; ++i) {
            int row = row0 + i * 64;
            int csw = (c0 ^ (row & 3)) << 3;
            gl_lds16(&Woh[(size_t)(nb * 128 + row) * D_MODEL + kb + csw],
                     &Bb[buf][(i * 256 + w * 64) * 8]);
        }
    };
    auto compute = [&](int buf) {
        sh8 af[2], bf[4];
#pragma unroll
        for (int mi = 0; mi < 2; ++mi) {
            int row = wr * 32 + mi * 16 + fr;
            af[mi] = *(const sh8*)&Ab[buf][(row << 5) + ((g ^ (row & 3)) << 3)];
        }
#pragma unroll
        for (int ni = 0; ni < 4; ++ni) {
            int row = wc * 64 + ni * 16 + fr;
            bf[ni] = *(const sh8*)&Bb[buf][(row << 5) + ((g ^ (row & 3)) << 3)];
        }
#pragma unroll
        for (int mi = 0; mi < 2; ++mi)
#pragma unroll
            for (int ni = 0; ni < 4; ++ni)
                acc[mi][ni] = __builtin_amdgcn_mfma_f32_16x16x32_bf16(af[mi], bf[ni], acc[mi][ni], 0, 0, 0);
    };

    stage(0, 0);
    asm volatile("s_waitcnt vmcnt(0)" ::: "memory");
    __builtin_amdgcn_s_barrier();

    int cur = 0;
#pragma unroll 1
    for (int kt = 0; kt < 31; ++kt) {
        stage(kt + 1, cur ^ 1);
        compute(cur);
        asm volatile("s_waitcnt vmcnt(0)" ::: "memory");
        __builtin_amdgcn_s_barrier();
        cur ^= 1;
    }
    compute(cur);

#pragma unroll
    for (int mi = 0; mi < 2; ++mi)
#pragma unroll
        for (int ni = 0; ni < 4; ++ni)
#pragma unroll
            for (int r = 0; r < 4; ++r) {
                int m = mb * 64 + wr * 32 + mi * 16 + qrhi + r;
                int n = nb * 128 + wc * 64 + ni * 16 + fr;
                out[(size_t)m * D_MODEL + n] = acc[mi][ni][r];
            }
}

extern "C" void kernel_launch(void* const* d_in, const int* in_sizes, int n_in,
                              void* d_out, int out_size, void* d_ws, size_t ws_size,
                              hipStream_t stream) {
    const float* hidden = (const float*)d_in[0];
    const float* Wq = (const float*)d_in[1];
    const float* Wk = (const float*)d_in[2];
    const float* Wv = (const float*)d_in[3];
    const float* Wo = (const float*)d_in[4];
    const float* rel = (const float*)d_in[5];
    float* out = (float*)d_out;

    const size_t NE = (size_t)NB * NH * SEQ * HD;   // 4,194,304 (x2B = 8MB)
    const size_t WE = (size_t)D_MODEL * D_MODEL;    // 1,048,576 (x2B = 2MB)
    char* ws = (char*)d_ws;
    short* Qh = (short*)(ws + 0 * NE * 2);
    short* Ql = (short*)(ws + 1 * NE * 2);
    short* Kh = (short*)(ws + 2 * NE * 2);
    short* Kl = (short*)(ws + 3 * NE * 2);
    short* Vt = (short*)(ws + 4 * NE * 2);          // [32,40)MB; dead after attn
    char* wsp = ws + 5 * NE * 2;                    // 40MB mark
    short* Wqh = (short*)(wsp + 0 * WE * 2);
    short* Wql = (short*)(wsp + 1 * WE * 2);
    short* Wkh = (short*)(wsp + 2 * WE * 2);
    short* Wkl = (short*)(wsp + 3 * WE * 2);
    short* Wvh = (short*)(wsp + 4 * WE * 2);
    short* Wvl = (short*)(wsp + 5 * WE * 2);
    short* Woh = (short*)(wsp + 6 * WE * 2);        // survives until o_gemm
    float* bias = (float*)(wsp + 7 * WE * 2);       // 54MB mark, 256KB
    float* plB = (float*)(wsp + 7 * WE * 2 + 262144);  // 512KB partial l
    short* ctxb = Vt;   // alias: Vt dead after attn; combine writes here

    // Hh/Hl then partial-O both live in d_out (16MB), phase-disjoint.
    short* Hh = (short*)d_out;
    short* Hl = Hh + NE;
    short* poB = (short*)d_out;

    bias_kernel<<<dim3(256), dim3(256), 0, stream>>>(rel, bias);
    presplit_kernel<<<dim3(4096), dim3(256), 0, stream>>>(hidden, Hh, Hl, 1048576);
    presplitW_kernel<<<dim3(4096), dim3(256), 0, stream>>>(
        Wq, Wk, Wv, Wo, Wqh, Wql, Wkh, Wkl, Wvh, Wvl, Woh);
    qkv_gemm<<<dim3(24, 32), dim3(256), 0, stream>>>(
        Hh, Hl, Wqh, Wql, Wkh, Wkl, Wvh, Wvl, Qh, Ql, Kh, Kl, Vt);
    attn_kernel<<<dim3(16, 16, 4), dim3(256), 0, stream>>>(
        Qh, Ql, Kh, Kl, Vt, bias, poB, plB);
    combine_kernel<<<dim3(2048), dim3(256), 0, stream>>>(poB, plB, ctxb);
    o_gemm<<<dim3(8, 64), dim3(256), 0, stream>>>(ctxb, Woh, out);
}

// Round 14
// 224.301 us; speedup vs baseline: 1.2413x; 1.2413x over previous
//
#include <hip/hip_runtime.h>
#include <hip/hip_bf16.h>

#define D_MODEL 1024
#define NH 16
#define HD 64
#define SEQ 2048
#define NB 2
#define LOG2E 1.4426950408889634f

typedef __attribute__((ext_vector_type(8))) short sh8;
typedef __attribute__((ext_vector_type(4))) short sh4;
typedef __attribute__((ext_vector_type(4))) float fx4;

__device__ __forceinline__ short f2bf(float x) {
    union { float f; unsigned u; } v; v.f = x;
    unsigned r = (v.u + 0x7FFFu + ((v.u >> 16) & 1u)) >> 16;
    return (short)r;
}
__device__ __forceinline__ float bf2f(short b) {
    union { float f; unsigned u; } v; v.u = ((unsigned)(unsigned short)b) << 16;
    return v.f;
}
__device__ __forceinline__ short truncbf(float x) {
    union { float f; unsigned u; } v; v.f = x;
    return (short)(v.u >> 16);
}

// async global->LDS, 16B per lane. LDS dest linear: wave base + lane*16.
__device__ __forceinline__ void gl_lds16(const short* g, short* l) {
    __builtin_amdgcn_global_load_lds(
        (const __attribute__((address_space(1))) void*)(uintptr_t)(const void*)g,
        (__attribute__((address_space(3))) void*)(uintptr_t)(void*)l, 16, 0, 0);
}

// ---------------- bias table: bt[h][delta+2047] = (bias - 40) * log2(e) ------
__global__ __launch_bounds__(256) void bias_kernel(const float* __restrict__ rel_emb,
                                                   float* __restrict__ bt) {
    int i = blockIdx.x * 256 + threadIdx.x;
    if (i >= NH * 4095) return;
    int h = i / 4095;
    int delta = (i % 4095) - 2047;
    int rb = delta > 0 ? 16 : 0;
    int ad = delta < 0 ? -delta : delta;
    int bidx;
    if (ad < 8) bidx = ad;
    else if (ad < 12) bidx = 8;
    else if (ad < 16) bidx = 9;
    else if (ad < 23) bidx = 10;
    else if (ad < 32) bidx = 11;
    else if (ad < 46) bidx = 12;
    else if (ad < 64) bidx = 13;
    else if (ad < 91) bidx = 14;
    else bidx = 15;
    bt[h * 4095 + (delta + 2047)] = (rel_emb[(rb + bidx) * NH + h] - 40.0f) * LOG2E;
}

// ---------------- presplit hidden: fp32 -> (hi, lo) bf16 ----------------------
__global__ __launch_bounds__(256) void presplit_kernel(const float* __restrict__ src,
                                                       short* __restrict__ hi,
                                                       short* __restrict__ lo, int n4) {
    int idx = blockIdx.x * 256 + threadIdx.x;
    if (idx >= n4) return;
    float4 v = ((const float4*)src)[idx];
    const float* p = (const float*)&v;
    sh4 h, l;
#pragma unroll
    for (int j = 0; j < 4; ++j) {
        short hh = f2bf(p[j]);
        h[j] = hh;
        l[j] = f2bf(p[j] - bf2f(hh));
    }
    *(sh4*)&hi[(size_t)idx * 4] = h;
    *(sh4*)&lo[(size_t)idx * 4] = l;
}

// ---------------- fused weight presplit: Wq/Wk/Wv hi+lo, Wo hi ----------------
__global__ __launch_bounds__(256) void presplitW_kernel(
    const float* __restrict__ Wq, const float* __restrict__ Wk,
    const float* __restrict__ Wv, const float* __restrict__ Wo,
    short* __restrict__ Wqh, short* __restrict__ Wql,
    short* __restrict__ Wkh, short* __restrict__ Wkl,
    short* __restrict__ Wvh, short* __restrict__ Wvl,
    short* __restrict__ Woh) {
    int idx = blockIdx.x * 256 + threadIdx.x;   // 4 x 262144
    int sel = idx >> 18;
    int loc = idx & 0x3FFFF;
    const float* src = sel == 0 ? Wq : (sel == 1 ? Wk : (sel == 2 ? Wv : Wo));
    float4 v = ((const float4*)src)[loc];
    const float* p = (const float*)&v;
    sh4 h, l;
#pragma unroll
    for (int j = 0; j < 4; ++j) {
        short hh = f2bf(p[j]);
        h[j] = hh;
        l[j] = f2bf(p[j] - bf2f(hh));
    }
    if (sel == 3) {
        *(sh4*)&Woh[(size_t)loc * 4] = h;
    } else {
        short* hi = sel == 0 ? Wqh : (sel == 1 ? Wkh : Wvh);
        short* lo = sel == 0 ? Wql : (sel == 1 ? Wkl : Wvl);
        *(sh4*)&hi[(size_t)loc * 4] = h;
        *(sh4*)&lo[(size_t)loc * 4] = l;
    }
}

// ---------------- QKV GEMM v7: Q/K bf16x3, V single-pass (bf16 output) -------
__global__ __launch_bounds__(256, 3) void qkv_gemm(
    const short* __restrict__ Hh, const short* __restrict__ Hl,
    const short* __restrict__ Wqh, const short* __restrict__ Wql,
    const short* __restrict__ Wkh, const short* __restrict__ Wkl,
    const short* __restrict__ Wvh, const short* __restrict__ Wvl,
    short* __restrict__ Qh, short* __restrict__ Ql,
    short* __restrict__ Kh, short* __restrict__ Kl, short* __restrict__ Vt) {
    __shared__ short Ah[4096];
    __shared__ short Al[4096];
    __shared__ short Bh[4096];
    __shared__ short Bl[4096];

    int t = threadIdx.x;
    int lane = t & 63, w = t >> 6;
    int wr = w >> 1, wc = w & 1;
    int fr = lane & 15, g = lane >> 4;
    int qrhi = g << 2;

    int lin = blockIdx.y * 24 + blockIdx.x;
    int xcd = lin & 7, i5 = lin >> 3;
    int nb = xcd * 3 + i5 % 3;
    int mb = i5 / 3;

    int proj = (nb * 128) >> 10;
    int nlocal = (nb * 128) & 1023;
    const short* Wh = proj == 0 ? Wqh : (proj == 1 ? Wkh : Wvh);
    const short* Wl = proj == 0 ? Wql : (proj == 1 ? Wkl : Wvl);

    const short* Ahb = Hh + (size_t)(mb * 128) * D_MODEL;
    const short* Alb = Hl + (size_t)(mb * 128) * D_MODEL;
    const short* Bhb = Wh + (size_t)nlocal * D_MODEL;
    const short* Blb = Wl + (size_t)nlocal * D_MODEL;

    fx4 acc[4][4];
#pragma unroll
    for (int i = 0; i < 4; ++i)
#pragma unroll
        for (int j = 0; j < 4; ++j) acc[i][j] = (fx4){0.f, 0.f, 0.f, 0.f};

    auto stage = [&](int kt) {
        int kb = kt * 32;
#pragma unroll
        for (int i = 0; i < 2; ++i) {
            int idx = i * 256 + t;
            int row = idx >> 2;
            int csw = ((idx & 3) ^ (row & 3)) << 3;
            size_t go = (size_t)row * D_MODEL + kb + csw;
            int dst = (i * 256 + w * 64) * 8;
            gl_lds16(Ahb + go, &Ah[dst]);
            gl_lds16(Bhb + go, &Bh[dst]);
            if (proj != 2) {        // V: single-pass, no lo staging
                gl_lds16(Alb + go, &Al[dst]);
                gl_lds16(Blb + go, &Bl[dst]);
            }
        }
    };
    auto compute = [&]() {
        sh8 afh[4], bfh[4];
#pragma unroll
        for (int mi = 0; mi < 4; ++mi) {
            int row = wr * 64 + mi * 16 + fr;
            afh[mi] = *(const sh8*)&Ah[row * 32 + ((g ^ (row & 3)) << 3)];
        }
#pragma unroll
        for (int ni = 0; ni < 4; ++ni) {
            int row = wc * 64 + ni * 16 + fr;
            bfh[ni] = *(const sh8*)&Bh[row * 32 + ((g ^ (row & 3)) << 3)];
        }
#pragma unroll
        for (int mi = 0; mi < 4; ++mi)
#pragma unroll
            for (int ni = 0; ni < 4; ++ni)
                acc[mi][ni] = __builtin_amdgcn_mfma_f32_16x16x32_bf16(afh[mi], bfh[ni], acc[mi][ni], 0, 0, 0);
        if (proj != 2) {
            sh8 afl[4], bfl[4];
#pragma unroll
            for (int mi = 0; mi < 4; ++mi) {
                int row = wr * 64 + mi * 16 + fr;
                afl[mi] = *(const sh8*)&Al[row * 32 + ((g ^ (row & 3)) << 3)];
            }
#pragma unroll
            for (int ni = 0; ni < 4; ++ni) {
                int row = wc * 64 + ni * 16 + fr;
                bfl[ni] = *(const sh8*)&Bl[row * 32 + ((g ^ (row & 3)) << 3)];
            }
#pragma unroll
            for (int mi = 0; mi < 4; ++mi)
#pragma unroll
                for (int ni = 0; ni < 4; ++ni)
                    acc[mi][ni] = __builtin_amdgcn_mfma_f32_16x16x32_bf16(afh[mi], bfl[ni], acc[mi][ni], 0, 0, 0);
#pragma unroll
            for (int mi = 0; mi < 4; ++mi)
#pragma unroll
                for (int ni = 0; ni < 4; ++ni)
                    acc[mi][ni] = __builtin_amdgcn_mfma_f32_16x16x32_bf16(afl[mi], bfh[ni], acc[mi][ni], 0, 0, 0);
        }
    };

#pragma unroll 1
    for (int kt = 0; kt < 32; ++kt) {
        __syncthreads();
        stage(kt);
        __syncthreads();
        compute();
    }

#pragma unroll
    for (int mi = 0; mi < 4; ++mi)
#pragma unroll
        for (int ni = 0; ni < 4; ++ni)
#pragma unroll
            for (int r = 0; r < 4; ++r) {
                int m = mb * 128 + wr * 64 + mi * 16 + qrhi + r;
                int n = nb * 128 + wc * 64 + ni * 16 + fr;
                int nn = n & 1023;
                int h = nn >> 6, d = nn & 63;
                int b = m >> 11, s = m & 2047;
                size_t bh = (size_t)(b * NH + h);
                float val = acc[mi][ni][r];
                if (proj == 0) {
                    short hh = f2bf(val);
                    Qh[(bh * SEQ + s) * HD + d] = hh;
                    Ql[(bh * SEQ + s) * HD + d] = f2bf(val - bf2f(hh));
                } else if (proj == 1) {
                    short hh = f2bf(val);
                    Kh[(bh * SEQ + s) * HD + d] = hh;
                    Kl[(bh * SEQ + s) * HD + d] = f2bf(val - bf2f(hh));
                } else {
                    Vt[(bh * HD + d) * SEQ + s] = f2bf(val);
                }
            }
}

// swizzled LDS index (shorts): row-major [64][64], XOR bank swizzle
#define SW(row, scol) (((row) << 6) + ((scol) ^ (((row) & 7) << 3)))

// ---------------- flash attention v6 (R11 exact): kt-split, glds, (256,3) ----
__global__ __launch_bounds__(256, 3) void attn_kernel(
    const short* __restrict__ Qhg, const short* __restrict__ Qlg,
    const short* __restrict__ Khg, const short* __restrict__ Klg,
    const short* __restrict__ Vtg, const float* __restrict__ biasS,
    short* __restrict__ poB, float* __restrict__ plB) {
    __shared__ short Ks[64 * 64];
    __shared__ short Kls[64 * 64];
    __shared__ short Vs[64 * 64];
    __shared__ short Pl[4 * 16 * 72];
    __shared__ float Bt[192];

    int t = threadIdx.x;
    int lane = t & 63, w = t >> 6;
    int fr = lane & 15, g = lane >> 4;
    int fk = g << 3;
    int qrhi = g << 2;
    int qt = blockIdx.x, h = blockIdx.y;
    int b = blockIdx.z >> 1, half = blockIdx.z & 1;
    int qbase = qt * 128;
    int ktbase = half * 16;
    size_t bh = (size_t)(b * NH + h);

    sh8 qh[2][2], ql[2][2];
#pragma unroll
    for (int qg = 0; qg < 2; ++qg)
#pragma unroll
        for (int ks = 0; ks < 2; ++ks) {
            int row = qbase + w * 32 + qg * 16 + fr;
            qh[qg][ks] = *(const sh8*)&Qhg[(bh * SEQ + row) * HD + ks * 32 + fk];
            ql[qg][ks] = *(const sh8*)&Qlg[(bh * SEQ + row) * HD + ks * 32 + fk];
        }

    float lrow[2][4];
    fx4 o[2][4];
#pragma unroll
    for (int qg = 0; qg < 2; ++qg) {
#pragma unroll
        for (int r = 0; r < 4; ++r) lrow[qg][r] = 0.f;
#pragma unroll
        for (int di = 0; di < 4; ++di) o[qg][di] = (fx4){0.f, 0.f, 0.f, 0.f};
    }

    // hoisted kt-invariant LDS offsets
    int fo[2][4];
#pragma unroll
    for (int ks = 0; ks < 2; ++ks)
#pragma unroll
        for (int i = 0; i < 4; ++i) fo[ks][i] = SW(i * 16 + fr, ks * 32 + fk);
    int shftw = ((qrhi >> 3) & 1) << 3;
    int shftr = ((fr >> 3) & 1) << 3;
    int pbase = w * 1152;
    int pw = pbase + qrhi * 72 + fr + shftw;
    int pr0 = pbase + fr * 72 + fk + shftr;

    // glds staging: linear dest chunk cd; source chunk = p ^ (row&7)
    int sd[2], srow[2], schunk[2];
#pragma unroll
    for (int i = 0; i < 2; ++i) {
        int cd = i * 256 + t;
        int row = cd >> 3, p = cd & 7;
        sd[i] = cd * 8;
        srow[i] = row;
        schunk[i] = (p ^ (row & 7)) << 3;
    }

    const short* kbase = Khg + bh * SEQ * HD;
    const short* klbase = Klg + bh * SEQ * HD;
    const short* vbase = Vtg + bh * HD * SEQ;

    for (int ktl = 0; ktl < 16; ++ktl) {
        int kt = ktbase + ktl;
        __syncthreads();    // previous iteration's LDS reads complete
#pragma unroll
        for (int i = 0; i < 2; ++i) {
            gl_lds16(kbase + (size_t)(kt * 64 + srow[i]) * HD + schunk[i], &Ks[sd[i]]);
            gl_lds16(klbase + (size_t)(kt * 64 + srow[i]) * HD + schunk[i], &Kls[sd[i]]);
            gl_lds16(vbase + (size_t)srow[i] * SEQ + kt * 64 + schunk[i], &Vs[sd[i]]);
        }
        if (t < 191) Bt[t] = biasS[h * 4095 + 2047 + (kt * 64 - qbase - 127) + t];
        __syncthreads();    // glds + bias landed

        // QK^T (bf16x3)
        fx4 sc[2][4];
#pragma unroll
        for (int qg = 0; qg < 2; ++qg)
#pragma unroll
            for (int ni = 0; ni < 4; ++ni) sc[qg][ni] = (fx4){0.f, 0.f, 0.f, 0.f};
        __builtin_amdgcn_s_setprio(1);
#pragma unroll
        for (int ks = 0; ks < 2; ++ks)
#pragma unroll
            for (int ni = 0; ni < 4; ++ni) {
                sh8 kf = *(const sh8*)&Ks[fo[ks][ni]];
                sh8 klf = *(const sh8*)&Kls[fo[ks][ni]];
#pragma unroll
                for (int qg = 0; qg < 2; ++qg) {
                    sc[qg][ni] = __builtin_amdgcn_mfma_f32_16x16x32_bf16(qh[qg][ks], kf, sc[qg][ni], 0, 0, 0);
                    sc[qg][ni] = __builtin_amdgcn_mfma_f32_16x16x32_bf16(ql[qg][ks], kf, sc[qg][ni], 0, 0, 0);
                    sc[qg][ni] = __builtin_amdgcn_mfma_f32_16x16x32_bf16(qh[qg][ks], klf, sc[qg][ni], 0, 0, 0);
                }
            }
        __builtin_amdgcn_s_setprio(0);

        // per-qg: softmax -> P -> PV
#pragma unroll
        for (int qg = 0; qg < 2; ++qg) {
#pragma unroll
            for (int r = 0; r < 4; ++r) {
                int bidx0 = 127 + fr - (w * 32 + qg * 16 + qrhi + r);
                float psum = 0.f;
#pragma unroll
                for (int ni = 0; ni < 4; ++ni) {
                    float p = exp2f(fmaf(sc[qg][ni][r], LOG2E, Bt[bidx0 + ni * 16]));
                    sc[qg][ni][r] = p;
                    psum += p;
                }
                lrow[qg][r] += psum;
#pragma unroll
                for (int ni = 0; ni < 4; ++ni)
                    Pl[pw + r * 72 + ni * 16] = truncbf(sc[qg][ni][r]);
            }
            sh8 pa0 = *(const sh8*)&Pl[pr0];
            sh8 pa1 = *(const sh8*)&Pl[pr0 + 32];
            __builtin_amdgcn_s_setprio(1);
#pragma unroll
            for (int di = 0; di < 4; ++di) {
                sh8 vb0 = *(const sh8*)&Vs[fo[0][di]];
                sh8 vb1 = *(const sh8*)&Vs[fo[1][di]];
                o[qg][di] = __builtin_amdgcn_mfma_f32_16x16x32_bf16(pa0, vb0, o[qg][di], 0, 0, 0);
                o[qg][di] = __builtin_amdgcn_mfma_f32_16x16x32_bf16(pa1, vb1, o[qg][di], 0, 0, 0);
            }
            __builtin_amdgcn_s_setprio(0);
        }
    }

#pragma unroll
    for (int qg = 0; qg < 2; ++qg)
#pragma unroll
        for (int r = 0; r < 4; ++r) {
#pragma unroll
            for (int off = 1; off < 16; off <<= 1)
                lrow[qg][r] += __shfl_xor(lrow[qg][r], off, 64);
        }

    // epilogue: normalized partial O (bf16) + partial l (f32)
    short* po = poB + (size_t)half * (NB * SEQ * (size_t)D_MODEL);
    float* pl = plB + (size_t)half * (NB * NH * SEQ);
#pragma unroll
    for (int qg = 0; qg < 2; ++qg)
#pragma unroll
        for (int di = 0; di < 4; ++di)
#pragma unroll
            for (int r = 0; r < 4; ++r) {
                int q = qbase + w * 32 + qg * 16 + qrhi + r;
                int d = di * 16 + fr;
                po[((size_t)b * SEQ + q) * D_MODEL + h * HD + d] =
                    f2bf(o[qg][di][r] / lrow[qg][r]);
            }
    if (fr == 0) {
#pragma unroll
        for (int qg = 0; qg < 2; ++qg)
#pragma unroll
            for (int r = 0; r < 4; ++r) {
                int q = qbase + w * 32 + qg * 16 + qrhi + r;
                pl[bh * SEQ + q] = lrow[qg][r];
            }
    }
}

// ---------------- combine: ctx = (l0*O0' + l1*O1') / (l0+l1), bf16 -----------
__global__ __launch_bounds__(256) void combine_kernel(
    const short* __restrict__ poB, const float* __restrict__ plB,
    short* __restrict__ ctx) {
    const size_t NEl = (size_t)NB * SEQ * D_MODEL;
    int idx = blockIdx.x * 256 + threadIdx.x;
    if (idx >= (int)(NEl / 8)) return;
    size_t e = (size_t)idx * 8;
    int c = (int)(e & 1023);
    int h = c >> 6;
    int bq = (int)(e >> 10);
    int b = bq >> 11, q = bq & 2047;
    sh8 a0 = *(const sh8*)&poB[e];
    sh8 a1 = *(const sh8*)&poB[NEl + e];
    int li = (b * NH + h) * SEQ + q;
    float l0 = plB[li];
    float l1 = plB[NB * NH * SEQ + li];
    float inv = 1.0f / (l0 + l1);
    float w0 = l0 * inv, w1 = l1 * inv;
    sh8 r;
#pragma unroll
    for (int j = 0; j < 8; ++j)
        r[j] = f2bf(bf2f(a0[j]) * w0 + bf2f(a1[j]) * w1);
    *(sh8*)&ctx[e] = r;
}

// ---------------- output projection: 64x128 tile, dbuf, gload_lds ------------
__global__ __launch_bounds__(256) void o_gemm(
    const short* __restrict__ Actx, const short* __restrict__ Woh,
    float* __restrict__ out) {
    __shared__ short Ab[2][2048];
    __shared__ short Bb[2][4096];

    int t = threadIdx.x;
    int lane = t & 63, w = t >> 6;
    int wr = w >> 1, wc = w & 1;
    int fr = lane & 15, g = lane >> 4;
    int qrhi = g << 2;

    int lin = blockIdx.y * 8 + blockIdx.x;      // 512 blocks
    int swz = (lin & 7) * 64 + (lin >> 3);
    int nb = swz & 7, mb = swz >> 3;

    fx4 acc[2][4];
#pragma unroll
    for (int i = 0; i < 2; ++i)
#pragma unroll
        for (int j = 0; j < 4; ++j) acc[i][j] = (fx4){0.f, 0.f, 0.f, 0.f};

    int row0 = t >> 2, c0 = t & 3;

    auto stage = [&](int kt, int buf) {
        int kb = kt * 32;
        {
            int row = row0;
            int csw = (c0 ^ (row & 3)) << 3;
            gl_lds16(&Actx[(size_t)(mb * 64 + row) * D_MODEL + kb + csw],
                     &Ab[buf][(w * 64) * 8]);
        }
#pragma unroll
        for (int i = 0; i < 2; ++i) {
            int row = row0 + i * 64;
            int csw = (c0 ^ (row & 3)) << 3;
            gl_lds16(&Woh[(size_t)(nb * 128 + row) * D_MODEL + kb + csw],
                     &Bb[buf][(i * 256 + w * 64) * 8]);
        }
    };
    auto compute = [&](int buf) {
        sh8 af[2], bf[4];
#pragma unroll
        for (int mi = 0; mi < 2; ++mi) {
            int row = wr * 32 + mi * 16 + fr;
            af[mi] = *(const sh8*)&Ab[buf][(row << 5) + ((g ^ (row & 3)) << 3)];
        }
#pragma unroll
        for (int ni = 0; ni < 4; ++ni) {
            int row = wc * 64 + ni * 16 + fr;
            bf[ni] = *(const sh8*)&Bb[buf][(row << 5) + ((g ^ (row & 3)) << 3)];
        }
#pragma unroll
        for (int mi = 0; mi < 2; ++mi)
#pragma unroll
            for (int ni = 0; ni < 4; ++ni)
                acc[mi][ni] = __builtin_amdgcn_mfma_f32_16x16x32_bf16(af[mi], bf[ni], acc[mi][ni], 0, 0, 0);
    };

    stage(0, 0);
    asm volatile("s_waitcnt vmcnt(0)" ::: "memory");
    __builtin_amdgcn_s_barrier();

    int cur = 0;
#pragma unroll 1
    for (int kt = 0; kt < 31; ++kt) {
        stage(kt + 1, cur ^ 1);
        compute(cur);
        asm volatile("s_waitcnt vmcnt(0)" ::: "memory");
        __builtin_amdgcn_s_barrier();
        cur ^= 1;
    }
    compute(cur);

#pragma unroll
    for (int mi = 0; mi < 2; ++mi)
#pragma unroll
        for (int ni = 0; ni < 4; ++ni)
#pragma unroll
            for (int r = 0; r < 4; ++r) {
                int m = mb * 64 + wr * 32 + mi * 16 + qrhi + r;
                int n = nb * 128 + wc * 64 + ni * 16 + fr;
                out[(size_t)m * D_MODEL + n] = acc[mi][ni][r];
            }
}

extern "C" void kernel_launch(void* const* d_in, const int* in_sizes, int n_in,
                              void* d_out, int out_size, void* d_ws, size_t ws_size,
                              hipStream_t stream) {
    const float* hidden = (const float*)d_in[0];
    const float* Wq = (const float*)d_in[1];
    const float* Wk = (const float*)d_in[2];
    const float* Wv = (const float*)d_in[3];
    const float* Wo = (const float*)d_in[4];
    const float* rel = (const float*)d_in[5];
    float* out = (float*)d_out;

    const size_t NE = (size_t)NB * NH * SEQ * HD;   // 4,194,304 (x2B = 8MB)
    const size_t WE = (size_t)D_MODEL * D_MODEL;    // 1,048,576 (x2B = 2MB)
    char* ws = (char*)d_ws;
    short* Qh = (short*)(ws + 0 * NE * 2);
    short* Ql = (short*)(ws + 1 * NE * 2);
    short* Kh = (short*)(ws + 2 * NE * 2);
    short* Kl = (short*)(ws + 3 * NE * 2);
    short* Vt = (short*)(ws + 4 * NE * 2);          // [32,40)MB; dead after attn
    char* wsp = ws + 5 * NE * 2;                    // 40MB mark
    short* Wqh = (short*)(wsp + 0 * WE * 2);
    short* Wql = (short*)(wsp + 1 * WE * 2);
    short* Wkh = (short*)(wsp + 2 * WE * 2);
    short* Wkl = (short*)(wsp + 3 * WE * 2);
    short* Wvh = (short*)(wsp + 4 * WE * 2);
    short* Wvl = (short*)(wsp + 5 * WE * 2);
    short* Woh = (short*)(wsp + 6 * WE * 2);        // survives until o_gemm
    float* bias = (float*)(wsp + 7 * WE * 2);       // 54MB mark, 256KB
    float* plB = (float*)(wsp + 7 * WE * 2 + 262144);  // 512KB partial l
    short* ctxb = Vt;   // alias: Vt dead after attn; combine writes here

    // Hh/Hl then partial-O both live in d_out (16MB), phase-disjoint.
    short* Hh = (short*)d_out;
    short* Hl = Hh + NE;
    short* poB = (short*)d_out;

    bias_kernel<<<dim3(256), dim3(256), 0, stream>>>(rel, bias);
    presplit_kernel<<<dim3(4096), dim3(256), 0, stream>>>(hidden, Hh, Hl, 1048576);
    presplitW_kernel<<<dim3(4096), dim3(256), 0, stream>>>(
        Wq, Wk, Wv, Wo, Wqh, Wql, Wkh, Wkl, Wvh, Wvl, Woh);
    qkv_gemm<<<dim3(24, 32), dim3(256), 0, stream>>>(
        Hh, Hl, Wqh, Wql, Wkh, Wkl, Wvh, Wvl, Qh, Ql, Kh, Kl, Vt);
    attn_kernel<<<dim3(16, 16, 4), dim3(256), 0, stream>>>(
        Qh, Ql, Kh, Kl, Vt, bias, poB, plB);
    combine_kernel<<<dim3(2048), dim3(256), 0, stream>>>(poB, plB, ctxb);
    o_gemm<<<dim3(8, 64), dim3(256), 0, stream>>>(ctxb, Woh, out);
}

// Round 15
// 210.779 us; speedup vs baseline: 1.3210x; 1.0642x over previous
//
#include <hip/hip_runtime.h>
#include <hip/hip_bf16.h>

#define D_MODEL 1024
#define NH 16
#define HD 64
#define SEQ 2048
#define NB 2
#define LOG2E 1.4426950408889634f

typedef __attribute__((ext_vector_type(8))) short sh8;
typedef __attribute__((ext_vector_type(4))) short sh4;
typedef __attribute__((ext_vector_type(4))) float fx4;

__device__ __forceinline__ short f2bf(float x) {
    union { float f; unsigned u; } v; v.f = x;
    unsigned r = (v.u + 0x7FFFu + ((v.u >> 16) & 1u)) >> 16;
    return (short)r;
}
__device__ __forceinline__ float bf2f(short b) {
    union { float f; unsigned u; } v; v.u = ((unsigned)(unsigned short)b) << 16;
    return v.f;
}
__device__ __forceinline__ short truncbf(float x) {
    union { float f; unsigned u; } v; v.f = x;
    return (short)(v.u >> 16);
}

// async global->LDS, 16B per lane. LDS dest linear: wave base + lane*16.
__device__ __forceinline__ void gl_lds16(const short* g, short* l) {
    __builtin_amdgcn_global_load_lds(
        (const __attribute__((address_space(1))) void*)(uintptr_t)(const void*)g,
        (__attribute__((address_space(3))) void*)(uintptr_t)(void*)l, 16, 0, 0);
}

// ---------------- bias table: bt[h][delta+2047] = (bias - 40) * log2(e) ------
__global__ __launch_bounds__(256) void bias_kernel(const float* __restrict__ rel_emb,
                                                   float* __restrict__ bt) {
    int i = blockIdx.x * 256 + threadIdx.x;
    if (i >= NH * 4095) return;
    int h = i / 4095;
    int delta = (i % 4095) - 2047;
    int rb = delta > 0 ? 16 : 0;
    int ad = delta < 0 ? -delta : delta;
    int bidx;
    if (ad < 8) bidx = ad;
    else if (ad < 12) bidx = 8;
    else if (ad < 16) bidx = 9;
    else if (ad < 23) bidx = 10;
    else if (ad < 32) bidx = 11;
    else if (ad < 46) bidx = 12;
    else if (ad < 64) bidx = 13;
    else if (ad < 91) bidx = 14;
    else bidx = 15;
    bt[h * 4095 + (delta + 2047)] = (rel_emb[(rb + bidx) * NH + h] - 40.0f) * LOG2E;
}

// ---------------- fused presplit: hidden (hi+lo) and all weights -------------
__global__ __launch_bounds__(256) void presplit_all(
    const float* __restrict__ hidden,
    const float* __restrict__ Wq, const float* __restrict__ Wk,
    const float* __restrict__ Wv, const float* __restrict__ Wo,
    short* __restrict__ Hh, short* __restrict__ Hl,
    short* __restrict__ Wqh, short* __restrict__ Wql,
    short* __restrict__ Wkh, short* __restrict__ Wkl,
    short* __restrict__ Wvh, short* __restrict__ Wvl,
    short* __restrict__ Woh) {
    int idx = blockIdx.x * 256 + threadIdx.x;   // 2,097,152 total
    const float* src;
    short *hi, *lo;
    int loc;
    bool wantLo = true;
    if (idx < 1048576) {
        src = hidden; hi = Hh; lo = Hl; loc = idx;
    } else {
        int j = idx - 1048576;
        int sel = j >> 18;
        loc = j & 0x3FFFF;
        if (sel == 0)      { src = Wq; hi = Wqh; lo = Wql; }
        else if (sel == 1) { src = Wk; hi = Wkh; lo = Wkl; }
        else if (sel == 2) { src = Wv; hi = Wvh; lo = Wvl; }
        else               { src = Wo; hi = Woh; lo = nullptr; wantLo = false; }
    }
    float4 v = ((const float4*)src)[loc];
    const float* p = (const float*)&v;
    sh4 h, l;
#pragma unroll
    for (int j = 0; j < 4; ++j) {
        short hh = f2bf(p[j]);
        h[j] = hh;
        l[j] = f2bf(p[j] - bf2f(hh));
    }
    *(sh4*)&hi[(size_t)loc * 4] = h;
    if (wantLo) *(sh4*)&lo[(size_t)loc * 4] = l;
}

// ---------------- QKV GEMM v8: Q bf16x3+split out, K bf16x3 (hi out), V 1-pass
__global__ __launch_bounds__(256, 3) void qkv_gemm(
    const short* __restrict__ Hh, const short* __restrict__ Hl,
    const short* __restrict__ Wqh, const short* __restrict__ Wql,
    const short* __restrict__ Wkh, const short* __restrict__ Wkl,
    const short* __restrict__ Wvh, const short* __restrict__ Wvl,
    short* __restrict__ Qh, short* __restrict__ Ql,
    short* __restrict__ Kh, short* __restrict__ Vt) {
    __shared__ short Ah[4096];
    __shared__ short Al[4096];
    __shared__ short Bh[4096];
    __shared__ short Bl[4096];

    int t = threadIdx.x;
    int lane = t & 63, w = t >> 6;
    int wr = w >> 1, wc = w & 1;
    int fr = lane & 15, g = lane >> 4;
    int qrhi = g << 2;

    int lin = blockIdx.y * 24 + blockIdx.x;
    int xcd = lin & 7, i5 = lin >> 3;
    int nb = xcd * 3 + i5 % 3;
    int mb = i5 / 3;

    int proj = (nb * 128) >> 10;
    int nlocal = (nb * 128) & 1023;
    const short* Wh = proj == 0 ? Wqh : (proj == 1 ? Wkh : Wvh);
    const short* Wl = proj == 0 ? Wql : (proj == 1 ? Wkl : Wvl);

    const short* Ahb = Hh + (size_t)(mb * 128) * D_MODEL;
    const short* Alb = Hl + (size_t)(mb * 128) * D_MODEL;
    const short* Bhb = Wh + (size_t)nlocal * D_MODEL;
    const short* Blb = Wl + (size_t)nlocal * D_MODEL;

    fx4 acc[4][4];
#pragma unroll
    for (int i = 0; i < 4; ++i)
#pragma unroll
        for (int j = 0; j < 4; ++j) acc[i][j] = (fx4){0.f, 0.f, 0.f, 0.f};

    auto stage = [&](int kt) {
        int kb = kt * 32;
#pragma unroll
        for (int i = 0; i < 2; ++i) {
            int idx = i * 256 + t;
            int row = idx >> 2;
            int csw = ((idx & 3) ^ (row & 3)) << 3;
            size_t go = (size_t)row * D_MODEL + kb + csw;
            int dst = (i * 256 + w * 64) * 8;
            gl_lds16(Ahb + go, &Ah[dst]);
            gl_lds16(Bhb + go, &Bh[dst]);
            if (proj != 2) {        // V: single-pass, no lo staging
                gl_lds16(Alb + go, &Al[dst]);
                gl_lds16(Blb + go, &Bl[dst]);
            }
        }
    };
    auto compute = [&]() {
        sh8 afh[4], bfh[4];
#pragma unroll
        for (int mi = 0; mi < 4; ++mi) {
            int row = wr * 64 + mi * 16 + fr;
            afh[mi] = *(const sh8*)&Ah[row * 32 + ((g ^ (row & 3)) << 3)];
        }
#pragma unroll
        for (int ni = 0; ni < 4; ++ni) {
            int row = wc * 64 + ni * 16 + fr;
            bfh[ni] = *(const sh8*)&Bh[row * 32 + ((g ^ (row & 3)) << 3)];
        }
#pragma unroll
        for (int mi = 0; mi < 4; ++mi)
#pragma unroll
            for (int ni = 0; ni < 4; ++ni)
                acc[mi][ni] = __builtin_amdgcn_mfma_f32_16x16x32_bf16(afh[mi], bfh[ni], acc[mi][ni], 0, 0, 0);
        if (proj != 2) {
            sh8 afl[4], bfl[4];
#pragma unroll
            for (int mi = 0; mi < 4; ++mi) {
                int row = wr * 64 + mi * 16 + fr;
                afl[mi] = *(const sh8*)&Al[row * 32 + ((g ^ (row & 3)) << 3)];
            }
#pragma unroll
            for (int ni = 0; ni < 4; ++ni) {
                int row = wc * 64 + ni * 16 + fr;
                bfl[ni] = *(const sh8*)&Bl[row * 32 + ((g ^ (row & 3)) << 3)];
            }
#pragma unroll
            for (int mi = 0; mi < 4; ++mi)
#pragma unroll
                for (int ni = 0; ni < 4; ++ni)
                    acc[mi][ni] = __builtin_amdgcn_mfma_f32_16x16x32_bf16(afh[mi], bfl[ni], acc[mi][ni], 0, 0, 0);
#pragma unroll
            for (int mi = 0; mi < 4; ++mi)
#pragma unroll
                for (int ni = 0; ni < 4; ++ni)
                    acc[mi][ni] = __builtin_amdgcn_mfma_f32_16x16x32_bf16(afl[mi], bfh[ni], acc[mi][ni], 0, 0, 0);
        }
    };

#pragma unroll 1
    for (int kt = 0; kt < 32; ++kt) {
        __syncthreads();
        stage(kt);
        __syncthreads();
        compute();
    }

#pragma unroll
    for (int mi = 0; mi < 4; ++mi)
#pragma unroll
        for (int ni = 0; ni < 4; ++ni)
#pragma unroll
            for (int r = 0; r < 4; ++r) {
                int m = mb * 128 + wr * 64 + mi * 16 + qrhi + r;
                int n = nb * 128 + wc * 64 + ni * 16 + fr;
                int nn = n & 1023;
                int h = nn >> 6, d = nn & 63;
                int b = m >> 11, s = m & 2047;
                size_t bh = (size_t)(b * NH + h);
                float val = acc[mi][ni][r];
                if (proj == 0) {
                    short hh = f2bf(val);
                    Qh[(bh * SEQ + s) * HD + d] = hh;
                    Ql[(bh * SEQ + s) * HD + d] = f2bf(val - bf2f(hh));
                } else if (proj == 1) {
                    Kh[(bh * SEQ + s) * HD + d] = f2bf(val);
                } else {
                    Vt[(bh * HD + d) * SEQ + s] = f2bf(val);
                }
            }
}

// swizzled LDS index (shorts): row-major [64][64], XOR bank swizzle
#define SW(row, scol) (((row) << 6) + ((scol) ^ (((row) & 7) << 3)))

// ---------------- flash attention v9: QK bf16x2 (K-lo dropped), 26.6KB LDS ---
__global__ __launch_bounds__(256, 3) void attn_kernel(
    const short* __restrict__ Qhg, const short* __restrict__ Qlg,
    const short* __restrict__ Khg, const short* __restrict__ Vtg,
    const float* __restrict__ biasS,
    short* __restrict__ poB, float* __restrict__ plB) {
    __shared__ short Ks[64 * 64];
    __shared__ short Vs[64 * 64];
    __shared__ short Pl[4 * 16 * 72];
    __shared__ float Bt[192];

    int t = threadIdx.x;
    int lane = t & 63, w = t >> 6;
    int fr = lane & 15, g = lane >> 4;
    int fk = g << 3;
    int qrhi = g << 2;
    int qt = blockIdx.x, h = blockIdx.y;
    int b = blockIdx.z >> 1, half = blockIdx.z & 1;
    int qbase = qt * 128;
    int ktbase = half * 16;
    size_t bh = (size_t)(b * NH + h);

    sh8 qh[2][2], ql[2][2];
#pragma unroll
    for (int qg = 0; qg < 2; ++qg)
#pragma unroll
        for (int ks = 0; ks < 2; ++ks) {
            int row = qbase + w * 32 + qg * 16 + fr;
            qh[qg][ks] = *(const sh8*)&Qhg[(bh * SEQ + row) * HD + ks * 32 + fk];
            ql[qg][ks] = *(const sh8*)&Qlg[(bh * SEQ + row) * HD + ks * 32 + fk];
        }

    float lrow[2][4];
    fx4 o[2][4];
#pragma unroll
    for (int qg = 0; qg < 2; ++qg) {
#pragma unroll
        for (int r = 0; r < 4; ++r) lrow[qg][r] = 0.f;
#pragma unroll
        for (int di = 0; di < 4; ++di) o[qg][di] = (fx4){0.f, 0.f, 0.f, 0.f};
    }

    // hoisted kt-invariant LDS offsets
    int fo[2][4];
#pragma unroll
    for (int ks = 0; ks < 2; ++ks)
#pragma unroll
        for (int i = 0; i < 4; ++i) fo[ks][i] = SW(i * 16 + fr, ks * 32 + fk);
    int shftw = ((qrhi >> 3) & 1) << 3;
    int shftr = ((fr >> 3) & 1) << 3;
    int pbase = w * 1152;
    int pw = pbase + qrhi * 72 + fr + shftw;
    int pr0 = pbase + fr * 72 + fk + shftr;

    // glds staging: linear dest chunk cd; source chunk = p ^ (row&7)
    int sd[2], srow[2], schunk[2];
#pragma unroll
    for (int i = 0; i < 2; ++i) {
        int cd = i * 256 + t;
        int row = cd >> 3, p = cd & 7;
        sd[i] = cd * 8;
        srow[i] = row;
        schunk[i] = (p ^ (row & 7)) << 3;
    }

    const short* kbase = Khg + bh * SEQ * HD;
    const short* vbase = Vtg + bh * HD * SEQ;

    for (int ktl = 0; ktl < 16; ++ktl) {
        int kt = ktbase + ktl;
        __syncthreads();    // previous iteration's LDS reads complete
#pragma unroll
        for (int i = 0; i < 2; ++i) {
            gl_lds16(kbase + (size_t)(kt * 64 + srow[i]) * HD + schunk[i], &Ks[sd[i]]);
            gl_lds16(vbase + (size_t)srow[i] * SEQ + kt * 64 + schunk[i], &Vs[sd[i]]);
        }
        if (t < 191) Bt[t] = biasS[h * 4095 + 2047 + (kt * 64 - qbase - 127) + t];
        __syncthreads();    // glds + bias landed

        // QK^T (bf16x2: (qh+ql)*kh)
        fx4 sc[2][4];
#pragma unroll
        for (int qg = 0; qg < 2; ++qg)
#pragma unroll
            for (int ni = 0; ni < 4; ++ni) sc[qg][ni] = (fx4){0.f, 0.f, 0.f, 0.f};
        __builtin_amdgcn_s_setprio(1);
#pragma unroll
        for (int ks = 0; ks < 2; ++ks)
#pragma unroll
            for (int ni = 0; ni < 4; ++ni) {
                sh8 kf = *(const sh8*)&Ks[fo[ks][ni]];
#pragma unroll
                for (int qg = 0; qg < 2; ++qg) {
                    sc[qg][ni] = __builtin_amdgcn_mfma_f32_16x16x32_bf16(qh[qg][ks], kf, sc[qg][ni], 0, 0, 0);
                    sc[qg][ni] = __builtin_amdgcn_mfma_f32_16x16x32_bf16(ql[qg][ks], kf, sc[qg][ni], 0, 0, 0);
                }
            }
        __builtin_amdgcn_s_setprio(0);

        // per-qg: softmax -> P -> PV
#pragma unroll
        for (int qg = 0; qg < 2; ++qg) {
#pragma unroll
            for (int r = 0; r < 4; ++r) {
                int bidx0 = 127 + fr - (w * 32 + qg * 16 + qrhi + r);
                float psum = 0.f;
#pragma unroll
                for (int ni = 0; ni < 4; ++ni) {
                    float p = exp2f(fmaf(sc[qg][ni][r], LOG2E, Bt[bidx0 + ni * 16]));
                    sc[qg][ni][r] = p;
                    psum += p;
                }
                lrow[qg][r] += psum;
#pragma unroll
                for (int ni = 0; ni < 4; ++ni)
                    Pl[pw + r * 72 + ni * 16] = truncbf(sc[qg][ni][r]);
            }
            sh8 pa0 = *(const sh8*)&Pl[pr0];
            sh8 pa1 = *(const sh8*)&Pl[pr0 + 32];
            __builtin_amdgcn_s_setprio(1);
#pragma unroll
            for (int di = 0; di < 4; ++di) {
                sh8 vb0 = *(const sh8*)&Vs[fo[0][di]];
                sh8 vb1 = *(const sh8*)&Vs[fo[1][di]];
                o[qg][di] = __builtin_amdgcn_mfma_f32_16x16x32_bf16(pa0, vb0, o[qg][di], 0, 0, 0);
                o[qg][di] = __builtin_amdgcn_mfma_f32_16x16x32_bf16(pa1, vb1, o[qg][di], 0, 0, 0);
            }
            __builtin_amdgcn_s_setprio(0);
        }
    }

#pragma unroll
    for (int qg = 0; qg < 2; ++qg)
#pragma unroll
        for (int r = 0; r < 4; ++r) {
#pragma unroll
            for (int off = 1; off < 16; off <<= 1)
                lrow[qg][r] += __shfl_xor(lrow[qg][r], off, 64);
        }

    // epilogue: normalized partial O (bf16) + partial l (f32)
    short* po = poB + (size_t)half * (NB * SEQ * (size_t)D_MODEL);
    float* pl = plB + (size_t)half * (NB * NH * SEQ);
#pragma unroll
    for (int qg = 0; qg < 2; ++qg)
#pragma unroll
        for (int di = 0; di < 4; ++di)
#pragma unroll
            for (int r = 0; r < 4; ++r) {
                int q = qbase + w * 32 + qg * 16 + qrhi + r;
                int d = di * 16 + fr;
                po[((size_t)b * SEQ + q) * D_MODEL + h * HD + d] =
                    f2bf(o[qg][di][r] / lrow[qg][r]);
            }
    if (fr == 0) {
#pragma unroll
        for (int qg = 0; qg < 2; ++qg)
#pragma unroll
            for (int r = 0; r < 4; ++r) {
                int q = qbase + w * 32 + qg * 16 + qrhi + r;
                pl[bh * SEQ + q] = lrow[qg][r];
            }
    }
}

// ---------------- combine: ctx = (l0*O0' + l1*O1') / (l0+l1), bf16 -----------
__global__ __launch_bounds__(256) void combine_kernel(
    const short* __restrict__ poB, const float* __restrict__ plB,
    short* __restrict__ ctx) {
    const size_t NEl = (size_t)NB * SEQ * D_MODEL;
    int idx = blockIdx.x * 256 + threadIdx.x;
    if (idx >= (int)(NEl / 8)) return;
    size_t e = (size_t)idx * 8;
    int c = (int)(e & 1023);
    int h = c >> 6;
    int bq = (int)(e >> 10);
    int b = bq >> 11, q = bq & 2047;
    sh8 a0 = *(const sh8*)&poB[e];
    sh8 a1 = *(const sh8*)&poB[NEl + e];
    int li = (b * NH + h) * SEQ + q;
    float l0 = plB[li];
    float l1 = plB[NB * NH * SEQ + li];
    float inv = 1.0f / (l0 + l1);
    float w0 = l0 * inv, w1 = l1 * inv;
    sh8 r;
#pragma unroll
    for (int j = 0; j < 8; ++j)
        r[j] = f2bf(bf2f(a0[j]) * w0 + bf2f(a1[j]) * w1);
    *(sh8*)&ctx[e] = r;
}

// ---------------- output projection: 64x128 tile, dbuf, gload_lds ------------
__global__ __launch_bounds__(256) void o_gemm(
    const short* __restrict__ Actx, const short* __restrict__ Woh,
    float* __restrict__ out) {
    __shared__ short Ab[2][2048];
    __shared__ short Bb[2][4096];

    int t = threadIdx.x;
    int lane = t & 63, w = t >> 6;
    int wr = w >> 1, wc = w & 1;
    int fr = lane & 15, g = lane >> 4;
    int qrhi = g << 2;

    int lin = blockIdx.y * 8 + blockIdx.x;      // 512 blocks
    int swz = (lin & 7) * 64 + (lin >> 3);
    int nb = swz & 7, mb = swz >> 3;

    fx4 acc[2][4];
#pragma unroll
    for (int i = 0; i < 2; ++i)
#pragma unroll
        for (int j = 0; j < 4; ++j) acc[i][j] = (fx4){0.f, 0.f, 0.f, 0.f};

    int row0 = t >> 2, c0 = t & 3;

    auto stage = [&](int kt, int buf) {
        int kb = kt * 32;
        {
            int row = row0;
            int csw = (c0 ^ (row & 3)) << 3;
            gl_lds16(&Actx[(size_t)(mb * 64 + row) * D_MODEL + kb + csw],
                     &Ab[buf][(w * 64) * 8]);
        }
#pragma unroll
        for (int i = 0; i < 2; ++i) {
            int row = row0 + i * 64;
            int csw = (c0 ^ (row & 3)) << 3;
            gl_lds16(&Woh[(size_t)(nb * 128 + row) * D_MODEL + kb + csw],
                     &Bb[buf][(i * 256 + w * 64) * 8]);
        }
    };
    auto compute = [&](int buf) {
        sh8 af[2], bf[4];
#pragma unroll
        for (int mi = 0; mi < 2; ++mi) {
            int row = wr * 32 + mi * 16 + fr;
            af[mi] = *(const sh8*)&Ab[buf][(row << 5) + ((g ^ (row & 3)) << 3)];
        }
#pragma unroll
        for (int ni = 0; ni < 4; ++ni) {
            int row = wc * 64 + ni * 16 + fr;
            bf[ni] = *(const sh8*)&Bb[buf][(row << 5) + ((g ^ (row & 3)) << 3)];
        }
#pragma unroll
        for (int mi = 0; mi < 2; ++mi)
#pragma unroll
            for (int ni = 0; ni < 4; ++ni)
                acc[mi][ni] = __builtin_amdgcn_mfma_f32_16x16x32_bf16(af[mi], bf[ni], acc[mi][ni], 0, 0, 0);
    };

    stage(0, 0);
    asm volatile("s_waitcnt vmcnt(0)" ::: "memory");
    __builtin_amdgcn_s_barrier();

    int cur = 0;
#pragma unroll 1
    for (int kt = 0; kt < 31; ++kt) {
        stage(kt + 1, cur ^ 1);
        compute(cur);
        asm volatile("s_waitcnt vmcnt(0)" ::: "memory");
        __builtin_amdgcn_s_barrier();
        cur ^= 1;
    }
    compute(cur);

#pragma unroll
    for (int mi = 0; mi < 2; ++mi)
#pragma unroll
        for (int ni = 0; ni < 4; ++ni)
#pragma unroll
            for (int r = 0; r < 4; ++r) {
                int m = mb * 64 + wr * 32 + mi * 16 + qrhi + r;
                int n = nb * 128 + wc * 64 + ni * 16 + fr;
                out[(size_t)m * D_MODEL + n] = acc[mi][ni][r];
            }
}

extern "C" void kernel_launch(void* const* d_in, const int* in_sizes, int n_in,
                              void* d_out, int out_size, void* d_ws, size_t ws_size,
                              hipStream_t stream) {
    const float* hidden = (const float*)d_in[0];
    const float* Wq = (const float*)d_in[1];
    const float* Wk = (const float*)d_in[2];
    const float* Wv = (const float*)d_in[3];
    const float* Wo = (const float*)d_in[4];
    const float* rel = (const float*)d_in[5];
    float* out = (float*)d_out;

    const size_t NE = (size_t)NB * NH * SEQ * HD;   // 4,194,304 (x2B = 8MB)
    const size_t WE = (size_t)D_MODEL * D_MODEL;    // 1,048,576 (x2B = 2MB)
    char* ws = (char*)d_ws;
    short* Qh = (short*)(ws + 0 * NE * 2);
    short* Ql = (short*)(ws + 1 * NE * 2);
    short* Kh = (short*)(ws + 2 * NE * 2);
    // (ws + 3*NE*2) slot unused (was Kl)
    short* Vt = (short*)(ws + 4 * NE * 2);          // [32,40)MB; dead after attn
    char* wsp = ws + 5 * NE * 2;                    // 40MB mark
    short* Wqh = (short*)(wsp + 0 * WE * 2);
    short* Wql = (short*)(wsp + 1 * WE * 2);
    short* Wkh = (short*)(wsp + 2 * WE * 2);
    short* Wkl = (short*)(wsp + 3 * WE * 2);
    short* Wvh = (short*)(wsp + 4 * WE * 2);
    short* Wvl = (short*)(wsp + 5 * WE * 2);
    short* Woh = (short*)(wsp + 6 * WE * 2);        // survives until o_gemm
    float* bias = (float*)(wsp + 7 * WE * 2);       // 54MB mark, 256KB
    float* plB = (float*)(wsp + 7 * WE * 2 + 262144);  // 512KB partial l
    short* ctxb = Vt;   // alias: Vt dead after attn; combine writes here

    // Hh/Hl then partial-O both live in d_out (16MB), phase-disjoint.
    short* Hh = (short*)d_out;
    short* Hl = Hh + NE;
    short* poB = (short*)d_out;

    bias_kernel<<<dim3(256), dim3(256), 0, stream>>>(rel, bias);
    presplit_all<<<dim3(8192), dim3(256), 0, stream>>>(
        hidden, Wq, Wk, Wv, Wo, Hh, Hl, Wqh, Wql, Wkh, Wkl, Wvh, Wvl, Woh);
    qkv_gemm<<<dim3(24, 32), dim3(256), 0, stream>>>(
        Hh, Hl, Wqh, Wql, Wkh, Wkl, Wvh, Wvl, Qh, Ql, Kh, Vt);
    attn_kernel<<<dim3(16, 16, 4), dim3(256), 0, stream>>>(
        Qh, Ql, Kh, Vt, bias, poB, plB);
    combine_kernel<<<dim3(2048), dim3(256), 0, stream>>>(poB, plB, ctxb);
    o_gemm<<<dim3(8, 64), dim3(256), 0, stream>>>(ctxb, Woh, out);
}

// Round 16
// 198.521 us; speedup vs baseline: 1.4025x; 1.0618x over previous
//
#include <hip/hip_runtime.h>
#include <hip/hip_bf16.h>

#define D_MODEL 1024
#define NH 16
#define HD 64
#define SEQ 2048
#define NB 2
#define LOG2E 1.4426950408889634f

typedef __attribute__((ext_vector_type(8))) short sh8;
typedef __attribute__((ext_vector_type(4))) short sh4;
typedef __attribute__((ext_vector_type(4))) float fx4;

__device__ __forceinline__ short f2bf(float x) {
    union { float f; unsigned u; } v; v.f = x;
    unsigned r = (v.u + 0x7FFFu + ((v.u >> 16) & 1u)) >> 16;
    return (short)r;
}
__device__ __forceinline__ float bf2f(short b) {
    union { float f; unsigned u; } v; v.u = ((unsigned)(unsigned short)b) << 16;
    return v.f;
}
__device__ __forceinline__ short truncbf(float x) {
    union { float f; unsigned u; } v; v.f = x;
    return (short)(v.u >> 16);
}

// async global->LDS, 16B per lane. LDS dest linear: wave base + lane*16.
__device__ __forceinline__ void gl_lds16(const short* g, short* l) {
    __builtin_amdgcn_global_load_lds(
        (const __attribute__((address_space(1))) void*)(uintptr_t)(const void*)g,
        (__attribute__((address_space(3))) void*)(uintptr_t)(void*)l, 16, 0, 0);
}

// ---------------- bias table: bt[h][delta+2047] = (bias - 40) * log2(e) ------
__global__ __launch_bounds__(256) void bias_kernel(const float* __restrict__ rel_emb,
                                                   float* __restrict__ bt) {
    int i = blockIdx.x * 256 + threadIdx.x;
    if (i >= NH * 4095) return;
    int h = i / 4095;
    int delta = (i % 4095) - 2047;
    int rb = delta > 0 ? 16 : 0;
    int ad = delta < 0 ? -delta : delta;
    int bidx;
    if (ad < 8) bidx = ad;
    else if (ad < 12) bidx = 8;
    else if (ad < 16) bidx = 9;
    else if (ad < 23) bidx = 10;
    else if (ad < 32) bidx = 11;
    else if (ad < 46) bidx = 12;
    else if (ad < 64) bidx = 13;
    else if (ad < 91) bidx = 14;
    else bidx = 15;
    bt[h * 4095 + (delta + 2047)] = (rel_emb[(rb + bidx) * NH + h] - 40.0f) * LOG2E;
}

// ---------------- fused presplit: hidden (hi+lo) and all weights -------------
__global__ __launch_bounds__(256) void presplit_all(
    const float* __restrict__ hidden,
    const float* __restrict__ Wq, const float* __restrict__ Wk,
    const float* __restrict__ Wv, const float* __restrict__ Wo,
    short* __restrict__ Hh, short* __restrict__ Hl,
    short* __restrict__ Wqh, short* __restrict__ Wql,
    short* __restrict__ Wkh, short* __restrict__ Wkl,
    short* __restrict__ Wvh, short* __restrict__ Wvl,
    short* __restrict__ Woh) {
    int idx = blockIdx.x * 256 + threadIdx.x;   // 2,097,152 total
    const float* src;
    short *hi, *lo;
    int loc;
    bool wantLo = true;
    if (idx < 1048576) {
        src = hidden; hi = Hh; lo = Hl; loc = idx;
    } else {
        int j = idx - 1048576;
        int sel = j >> 18;
        loc = j & 0x3FFFF;
        if (sel == 0)      { src = Wq; hi = Wqh; lo = Wql; }
        else if (sel == 1) { src = Wk; hi = Wkh; lo = Wkl; }
        else if (sel == 2) { src = Wv; hi = Wvh; lo = Wvl; }
        else               { src = Wo; hi = Woh; lo = nullptr; wantLo = false; }
    }
    float4 v = ((const float4*)src)[loc];
    const float* p = (const float*)&v;
    sh4 h, l;
#pragma unroll
    for (int j = 0; j < 4; ++j) {
        short hh = f2bf(p[j]);
        h[j] = hh;
        l[j] = f2bf(p[j] - bf2f(hh));
    }
    *(sh4*)&hi[(size_t)loc * 4] = h;
    if (wantLo) *(sh4*)&lo[(size_t)loc * 4] = l;
}

// ---------------- QKV GEMM v9: Q/K bf16x3 compute, plain-bf16 out; V 1-pass --
__global__ __launch_bounds__(256, 3) void qkv_gemm(
    const short* __restrict__ Hh, const short* __restrict__ Hl,
    const short* __restrict__ Wqh, const short* __restrict__ Wql,
    const short* __restrict__ Wkh, const short* __restrict__ Wkl,
    const short* __restrict__ Wvh, const short* __restrict__ Wvl,
    short* __restrict__ Qh, short* __restrict__ Kh, short* __restrict__ Vt) {
    __shared__ short Ah[4096];
    __shared__ short Al[4096];
    __shared__ short Bh[4096];
    __shared__ short Bl[4096];

    int t = threadIdx.x;
    int lane = t & 63, w = t >> 6;
    int wr = w >> 1, wc = w & 1;
    int fr = lane & 15, g = lane >> 4;
    int qrhi = g << 2;

    int lin = blockIdx.y * 24 + blockIdx.x;
    int xcd = lin & 7, i5 = lin >> 3;
    int nb = xcd * 3 + i5 % 3;
    int mb = i5 / 3;

    int proj = (nb * 128) >> 10;
    int nlocal = (nb * 128) & 1023;
    const short* Wh = proj == 0 ? Wqh : (proj == 1 ? Wkh : Wvh);
    const short* Wl = proj == 0 ? Wql : (proj == 1 ? Wkl : Wvl);

    const short* Ahb = Hh + (size_t)(mb * 128) * D_MODEL;
    const short* Alb = Hl + (size_t)(mb * 128) * D_MODEL;
    const short* Bhb = Wh + (size_t)nlocal * D_MODEL;
    const short* Blb = Wl + (size_t)nlocal * D_MODEL;

    fx4 acc[4][4];
#pragma unroll
    for (int i = 0; i < 4; ++i)
#pragma unroll
        for (int j = 0; j < 4; ++j) acc[i][j] = (fx4){0.f, 0.f, 0.f, 0.f};

    auto stage = [&](int kt) {
        int kb = kt * 32;
#pragma unroll
        for (int i = 0; i < 2; ++i) {
            int idx = i * 256 + t;
            int row = idx >> 2;
            int csw = ((idx & 3) ^ (row & 3)) << 3;
            size_t go = (size_t)row * D_MODEL + kb + csw;
            int dst = (i * 256 + w * 64) * 8;
            gl_lds16(Ahb + go, &Ah[dst]);
            gl_lds16(Bhb + go, &Bh[dst]);
            if (proj != 2) {        // V: single-pass, no lo staging
                gl_lds16(Alb + go, &Al[dst]);
                gl_lds16(Blb + go, &Bl[dst]);
            }
        }
    };
    auto compute = [&]() {
        sh8 afh[4], bfh[4];
#pragma unroll
        for (int mi = 0; mi < 4; ++mi) {
            int row = wr * 64 + mi * 16 + fr;
            afh[mi] = *(const sh8*)&Ah[row * 32 + ((g ^ (row & 3)) << 3)];
        }
#pragma unroll
        for (int ni = 0; ni < 4; ++ni) {
            int row = wc * 64 + ni * 16 + fr;
            bfh[ni] = *(const sh8*)&Bh[row * 32 + ((g ^ (row & 3)) << 3)];
        }
#pragma unroll
        for (int mi = 0; mi < 4; ++mi)
#pragma unroll
            for (int ni = 0; ni < 4; ++ni)
                acc[mi][ni] = __builtin_amdgcn_mfma_f32_16x16x32_bf16(afh[mi], bfh[ni], acc[mi][ni], 0, 0, 0);
        if (proj != 2) {
            sh8 afl[4], bfl[4];
#pragma unroll
            for (int mi = 0; mi < 4; ++mi) {
                int row = wr * 64 + mi * 16 + fr;
                afl[mi] = *(const sh8*)&Al[row * 32 + ((g ^ (row & 3)) << 3)];
            }
#pragma unroll
            for (int ni = 0; ni < 4; ++ni) {
                int row = wc * 64 + ni * 16 + fr;
                bfl[ni] = *(const sh8*)&Bl[row * 32 + ((g ^ (row & 3)) << 3)];
            }
#pragma unroll
            for (int mi = 0; mi < 4; ++mi)
#pragma unroll
                for (int ni = 0; ni < 4; ++ni)
                    acc[mi][ni] = __builtin_amdgcn_mfma_f32_16x16x32_bf16(afh[mi], bfl[ni], acc[mi][ni], 0, 0, 0);
#pragma unroll
            for (int mi = 0; mi < 4; ++mi)
#pragma unroll
                for (int ni = 0; ni < 4; ++ni)
                    acc[mi][ni] = __builtin_amdgcn_mfma_f32_16x16x32_bf16(afl[mi], bfh[ni], acc[mi][ni], 0, 0, 0);
        }
    };

#pragma unroll 1
    for (int kt = 0; kt < 32; ++kt) {
        __syncthreads();
        stage(kt);
        __syncthreads();
        compute();
    }

#pragma unroll
    for (int mi = 0; mi < 4; ++mi)
#pragma unroll
        for (int ni = 0; ni < 4; ++ni)
#pragma unroll
            for (int r = 0; r < 4; ++r) {
                int m = mb * 128 + wr * 64 + mi * 16 + qrhi + r;
                int n = nb * 128 + wc * 64 + ni * 16 + fr;
                int nn = n & 1023;
                int h = nn >> 6, d = nn & 63;
                int b = m >> 11, s = m & 2047;
                size_t bh = (size_t)(b * NH + h);
                float val = acc[mi][ni][r];
                if (proj == 0) {
                    Qh[(bh * SEQ + s) * HD + d] = f2bf(val);
                } else if (proj == 1) {
                    Kh[(bh * SEQ + s) * HD + d] = f2bf(val);
                } else {
                    Vt[(bh * HD + d) * SEQ + s] = f2bf(val);
                }
            }
}

// swizzled LDS index (shorts): row-major [64][64], XOR bank swizzle
#define SW(row, scol) (((row) << 6) + ((scol) ^ (((row) & 7) << 3)))

// ---------------- flash attention v10: QK plain bf16, kt-split ---------------
__global__ __launch_bounds__(256, 3) void attn_kernel(
    const short* __restrict__ Qhg, const short* __restrict__ Khg,
    const short* __restrict__ Vtg, const float* __restrict__ biasS,
    short* __restrict__ poB, float* __restrict__ plB) {
    __shared__ short Ks[64 * 64];
    __shared__ short Vs[64 * 64];
    __shared__ short Pl[4 * 16 * 72];
    __shared__ float Bt[192];

    int t = threadIdx.x;
    int lane = t & 63, w = t >> 6;
    int fr = lane & 15, g = lane >> 4;
    int fk = g << 3;
    int qrhi = g << 2;
    int qt = blockIdx.x, h = blockIdx.y;
    int b = blockIdx.z >> 1, half = blockIdx.z & 1;
    int qbase = qt * 128;
    int ktbase = half * 16;
    size_t bh = (size_t)(b * NH + h);

    sh8 qh[2][2];
#pragma unroll
    for (int qg = 0; qg < 2; ++qg)
#pragma unroll
        for (int ks = 0; ks < 2; ++ks) {
            int row = qbase + w * 32 + qg * 16 + fr;
            qh[qg][ks] = *(const sh8*)&Qhg[(bh * SEQ + row) * HD + ks * 32 + fk];
        }

    float lrow[2][4];
    fx4 o[2][4];
#pragma unroll
    for (int qg = 0; qg < 2; ++qg) {
#pragma unroll
        for (int r = 0; r < 4; ++r) lrow[qg][r] = 0.f;
#pragma unroll
        for (int di = 0; di < 4; ++di) o[qg][di] = (fx4){0.f, 0.f, 0.f, 0.f};
    }

    // hoisted kt-invariant LDS offsets
    int fo[2][4];
#pragma unroll
    for (int ks = 0; ks < 2; ++ks)
#pragma unroll
        for (int i = 0; i < 4; ++i) fo[ks][i] = SW(i * 16 + fr, ks * 32 + fk);
    int shftw = ((qrhi >> 3) & 1) << 3;
    int shftr = ((fr >> 3) & 1) << 3;
    int pbase = w * 1152;
    int pw = pbase + qrhi * 72 + fr + shftw;
    int pr0 = pbase + fr * 72 + fk + shftr;

    // glds staging: linear dest chunk cd; source chunk = p ^ (row&7)
    int sd[2], srow[2], schunk[2];
#pragma unroll
    for (int i = 0; i < 2; ++i) {
        int cd = i * 256 + t;
        int row = cd >> 3, p = cd & 7;
        sd[i] = cd * 8;
        srow[i] = row;
        schunk[i] = (p ^ (row & 7)) << 3;
    }

    const short* kbase = Khg + bh * SEQ * HD;
    const short* vbase = Vtg + bh * HD * SEQ;

    for (int ktl = 0; ktl < 16; ++ktl) {
        int kt = ktbase + ktl;
        __syncthreads();    // previous iteration's LDS reads complete
#pragma unroll
        for (int i = 0; i < 2; ++i) {
            gl_lds16(kbase + (size_t)(kt * 64 + srow[i]) * HD + schunk[i], &Ks[sd[i]]);
            gl_lds16(vbase + (size_t)srow[i] * SEQ + kt * 64 + schunk[i], &Vs[sd[i]]);
        }
        if (t < 191) Bt[t] = biasS[h * 4095 + 2047 + (kt * 64 - qbase - 127) + t];
        __syncthreads();    // glds + bias landed

        // QK^T (plain bf16: qh * kh)
        fx4 sc[2][4];
#pragma unroll
        for (int qg = 0; qg < 2; ++qg)
#pragma unroll
            for (int ni = 0; ni < 4; ++ni) sc[qg][ni] = (fx4){0.f, 0.f, 0.f, 0.f};
        __builtin_amdgcn_s_setprio(1);
#pragma unroll
        for (int ks = 0; ks < 2; ++ks)
#pragma unroll
            for (int ni = 0; ni < 4; ++ni) {
                sh8 kf = *(const sh8*)&Ks[fo[ks][ni]];
#pragma unroll
                for (int qg = 0; qg < 2; ++qg)
                    sc[qg][ni] = __builtin_amdgcn_mfma_f32_16x16x32_bf16(qh[qg][ks], kf, sc[qg][ni], 0, 0, 0);
            }
        __builtin_amdgcn_s_setprio(0);

        // per-qg: softmax -> P -> PV
#pragma unroll
        for (int qg = 0; qg < 2; ++qg) {
#pragma unroll
            for (int r = 0; r < 4; ++r) {
                int bidx0 = 127 + fr - (w * 32 + qg * 16 + qrhi + r);
                float psum = 0.f;
#pragma unroll
                for (int ni = 0; ni < 4; ++ni) {
                    float p = exp2f(fmaf(sc[qg][ni][r], LOG2E, Bt[bidx0 + ni * 16]));
                    sc[qg][ni][r] = p;
                    psum += p;
                }
                lrow[qg][r] += psum;
#pragma unroll
                for (int ni = 0; ni < 4; ++ni)
                    Pl[pw + r * 72 + ni * 16] = truncbf(sc[qg][ni][r]);
            }
            sh8 pa0 = *(const sh8*)&Pl[pr0];
            sh8 pa1 = *(const sh8*)&Pl[pr0 + 32];
            __builtin_amdgcn_s_setprio(1);
#pragma unroll
            for (int di = 0; di < 4; ++di) {
                sh8 vb0 = *(const sh8*)&Vs[fo[0][di]];
                sh8 vb1 = *(const sh8*)&Vs[fo[1][di]];
                o[qg][di] = __builtin_amdgcn_mfma_f32_16x16x32_bf16(pa0, vb0, o[qg][di], 0, 0, 0);
                o[qg][di] = __builtin_amdgcn_mfma_f32_16x16x32_bf16(pa1, vb1, o[qg][di], 0, 0, 0);
            }
            __builtin_amdgcn_s_setprio(0);
        }
    }

#pragma unroll
    for (int qg = 0; qg < 2; ++qg)
#pragma unroll
        for (int r = 0; r < 4; ++r) {
#pragma unroll
            for (int off = 1; off < 16; off <<= 1)
                lrow[qg][r] += __shfl_xor(lrow[qg][r], off, 64);
        }

    // epilogue: normalized partial O (bf16) + partial l (f32)
    short* po = poB + (size_t)half * (NB * SEQ * (size_t)D_MODEL);
    float* pl = plB + (size_t)half * (NB * NH * SEQ);
#pragma unroll
    for (int qg = 0; qg < 2; ++qg)
#pragma unroll
        for (int di = 0; di < 4; ++di)
#pragma unroll
            for (int r = 0; r < 4; ++r) {
                int q = qbase + w * 32 + qg * 16 + qrhi + r;
                int d = di * 16 + fr;
                po[((size_t)b * SEQ + q) * D_MODEL + h * HD + d] =
                    f2bf(o[qg][di][r] / lrow[qg][r]);
            }
    if (fr == 0) {
#pragma unroll
        for (int qg = 0; qg < 2; ++qg)
#pragma unroll
            for (int r = 0; r < 4; ++r) {
                int q = qbase + w * 32 + qg * 16 + qrhi + r;
                pl[bh * SEQ + q] = lrow[qg][r];
            }
    }
}

// ---------------- combine: ctx = (l0*O0' + l1*O1') / (l0+l1), bf16 -----------
__global__ __launch_bounds__(256) void combine_kernel(
    const short* __restrict__ poB, const float* __restrict__ plB,
    short* __restrict__ ctx) {
    const size_t NEl = (size_t)NB * SEQ * D_MODEL;
    int idx = blockIdx.x * 256 + threadIdx.x;
    if (idx >= (int)(NEl / 8)) return;
    size_t e = (size_t)idx * 8;
    int c = (int)(e & 1023);
    int h = c >> 6;
    int bq = (int)(e >> 10);
    int b = bq >> 11, q = bq & 2047;
    sh8 a0 = *(const sh8*)&poB[e];
    sh8 a1 = *(const sh8*)&poB[NEl + e];
    int li = (b * NH + h) * SEQ + q;
    float l0 = plB[li];
    float l1 = plB[NB * NH * SEQ + li];
    float inv = 1.0f / (l0 + l1);
    float w0 = l0 * inv, w1 = l1 * inv;
    sh8 r;
#pragma unroll
    for (int j = 0; j < 8; ++j)
        r[j] = f2bf(bf2f(a0[j]) * w0 + bf2f(a1[j]) * w1);
    *(sh8*)&ctx[e] = r;
}

// ---------------- output projection: 64x128 tile, dbuf, gload_lds ------------
__global__ __launch_bounds__(256) void o_gemm(
    const short* __restrict__ Actx, const short* __restrict__ Woh,
    float* __restrict__ out) {
    __shared__ short Ab[2][2048];
    __shared__ short Bb[2][4096];

    int t = threadIdx.x;
    int lane = t & 63, w = t >> 6;
    int wr = w >> 1, wc = w & 1;
    int fr = lane & 15, g = lane >> 4;
    int qrhi = g << 2;

    int lin = blockIdx.y * 8 + blockIdx.x;      // 512 blocks
    int swz = (lin & 7) * 64 + (lin >> 3);
    int nb = swz & 7, mb = swz >> 3;

    fx4 acc[2][4];
#pragma unroll
    for (int i = 0; i < 2; ++i)
#pragma unroll
        for (int j = 0; j < 4; ++j) acc[i][j] = (fx4){0.f, 0.f, 0.f, 0.f};

    int row0 = t >> 2, c0 = t & 3;

    auto stage = [&](int kt, int buf) {
        int kb = kt * 32;
        {
            int row = row0;
            int csw = (c0 ^ (row & 3)) << 3;
            gl_lds16(&Actx[(size_t)(mb * 64 + row) * D_MODEL + kb + csw],
                     &Ab[buf][(w * 64) * 8]);
        }
#pragma unroll
        for (int i = 0; i < 2; ++i) {
            int row = row0 + i * 64;
            int csw = (c0 ^ (row & 3)) << 3;
            gl_lds16(&Woh[(size_t)(nb * 128 + row) * D_MODEL + kb + csw],
                     &Bb[buf][(i * 256 + w * 64) * 8]);
        }
    };
    auto compute = [&](int buf) {
        sh8 af[2], bf[4];
#pragma unroll
        for (int mi = 0; mi < 2; ++mi) {
            int row = wr * 32 + mi * 16 + fr;
            af[mi] = *(const sh8*)&Ab[buf][(row << 5) + ((g ^ (row & 3)) << 3)];
        }
#pragma unroll
        for (int ni = 0; ni < 4; ++ni) {
            int row = wc * 64 + ni * 16 + fr;
            bf[ni] = *(const sh8*)&Bb[buf][(row << 5) + ((g ^ (row & 3)) << 3)];
        }
#pragma unroll
        for (int mi = 0; mi < 2; ++mi)
#pragma unroll
            for (int ni = 0; ni < 4; ++ni)
                acc[mi][ni] = __builtin_amdgcn_mfma_f32_16x16x32_bf16(af[mi], bf[ni], acc[mi][ni], 0, 0, 0);
    };

    stage(0, 0);
    asm volatile("s_waitcnt vmcnt(0)" ::: "memory");
    __builtin_amdgcn_s_barrier();

    int cur = 0;
#pragma unroll 1
    for (int kt = 0; kt < 31; ++kt) {
        stage(kt + 1, cur ^ 1);
        compute(cur);
        asm volatile("s_waitcnt vmcnt(0)" ::: "memory");
        __builtin_amdgcn_s_barrier();
        cur ^= 1;
    }
    compute(cur);

#pragma unroll
    for (int mi = 0; mi < 2; ++mi)
#pragma unroll
        for (int ni = 0; ni < 4; ++ni)
#pragma unroll
            for (int r = 0; r < 4; ++r) {
                int m = mb * 64 + wr * 32 + mi * 16 + qrhi + r;
                int n = nb * 128 + wc * 64 + ni * 16 + fr;
                out[(size_t)m * D_MODEL + n] = acc[mi][ni][r];
            }
}

extern "C" void kernel_launch(void* const* d_in, const int* in_sizes, int n_in,
                              void* d_out, int out_size, void* d_ws, size_t ws_size,
                              hipStream_t stream) {
    const float* hidden = (const float*)d_in[0];
    const float* Wq = (const float*)d_in[1];
    const float* Wk = (const float*)d_in[2];
    const float* Wv = (const float*)d_in[3];
    const float* Wo = (const float*)d_in[4];
    const float* rel = (const float*)d_in[5];
    float* out = (float*)d_out;

    const size_t NE = (size_t)NB * NH * SEQ * HD;   // 4,194,304 (x2B = 8MB)
    const size_t WE = (size_t)D_MODEL * D_MODEL;    // 1,048,576 (x2B = 2MB)
    char* ws = (char*)d_ws;
    short* Qh = (short*)(ws + 0 * NE * 2);
    short* Kh = (short*)(ws + 2 * NE * 2);
    short* Vt = (short*)(ws + 4 * NE * 2);          // [32,40)MB; dead after attn
    char* wsp = ws + 5 * NE * 2;                    // 40MB mark
    short* Wqh = (short*)(wsp + 0 * WE * 2);
    short* Wql = (short*)(wsp + 1 * WE * 2);
    short* Wkh = (short*)(wsp + 2 * WE * 2);
    short* Wkl = (short*)(wsp + 3 * WE * 2);
    short* Wvh = (short*)(wsp + 4 * WE * 2);
    short* Wvl = (short*)(wsp + 5 * WE * 2);
    short* Woh = (short*)(wsp + 6 * WE * 2);        // survives until o_gemm
    float* bias = (float*)(wsp + 7 * WE * 2);       // 54MB mark, 256KB
    float* plB = (float*)(wsp + 7 * WE * 2 + 262144);  // 512KB partial l
    short* ctxb = Vt;   // alias: Vt dead after attn; combine writes here

    // Hh/Hl then partial-O both live in d_out (16MB), phase-disjoint.
    short* Hh = (short*)d_out;
    short* Hl = Hh + NE;
    short* poB = (short*)d_out;

    bias_kernel<<<dim3(256), dim3(256), 0, stream>>>(rel, bias);
    presplit_all<<<dim3(8192), dim3(256), 0, stream>>>(
        hidden, Wq, Wk, Wv, Wo, Hh, Hl, Wqh, Wql, Wkh, Wkl, Wvh, Wvl, Woh);
    qkv_gemm<<<dim3(24, 32), dim3(256), 0, stream>>>(
        Hh, Hl, Wqh, Wql, Wkh, Wkl, Wvh, Wvl, Qh, Kh, Vt);
    attn_kernel<<<dim3(16, 16, 4), dim3(256), 0, stream>>>(
        Qh, Kh, Vt, bias, poB, plB);
    combine_kernel<<<dim3(2048), dim3(256), 0, stream>>>(poB, plB, ctxb);
    o_gemm<<<dim3(8, 64), dim3(256), 0, stream>>>(ctxb, Woh, out);
}

// Round 17
// 182.029 us; speedup vs baseline: 1.5296x; 1.0906x over previous
//
#include <hip/hip_runtime.h>
#include <hip/hip_bf16.h>

#define D_MODEL 1024
#define NH 16
#define HD 64
#define SEQ 2048
#define NB 2
#define LOG2E 1.4426950408889634f

typedef __attribute__((ext_vector_type(8))) short sh8;
typedef __attribute__((ext_vector_type(4))) short sh4;
typedef __attribute__((ext_vector_type(4))) float fx4;

__device__ __forceinline__ short f2bf(float x) {
    union { float f; unsigned u; } v; v.f = x;
    unsigned r = (v.u + 0x7FFFu + ((v.u >> 16) & 1u)) >> 16;
    return (short)r;
}
__device__ __forceinline__ float bf2f(short b) {
    union { float f; unsigned u; } v; v.u = ((unsigned)(unsigned short)b) << 16;
    return v.f;
}
__device__ __forceinline__ short truncbf(float x) {
    union { float f; unsigned u; } v; v.f = x;
    return (short)(v.u >> 16);
}
// bare v_exp_f32: args bounded above; deep-negative flushes to 0 (desired)
__device__ __forceinline__ float fexp2(float x) {
    float r;
    asm("v_exp_f32 %0, %1" : "=v"(r) : "v"(x));
    return r;
}

// async global->LDS, 16B per lane. LDS dest linear: wave base + lane*16.
__device__ __forceinline__ void gl_lds16(const short* g, short* l) {
    __builtin_amdgcn_global_load_lds(
        (const __attribute__((address_space(1))) void*)(uintptr_t)(const void*)g,
        (__attribute__((address_space(3))) void*)(uintptr_t)(void*)l, 16, 0, 0);
}

// ---------------- bias table: bt[h][delta+2047] = (bias - 40) * log2(e) ------
__global__ __launch_bounds__(256) void bias_kernel(const float* __restrict__ rel_emb,
                                                   float* __restrict__ bt) {
    int i = blockIdx.x * 256 + threadIdx.x;
    if (i >= NH * 4095) return;
    int h = i / 4095;
    int delta = (i % 4095) - 2047;
    int rb = delta > 0 ? 16 : 0;
    int ad = delta < 0 ? -delta : delta;
    int bidx;
    if (ad < 8) bidx = ad;
    else if (ad < 12) bidx = 8;
    else if (ad < 16) bidx = 9;
    else if (ad < 23) bidx = 10;
    else if (ad < 32) bidx = 11;
    else if (ad < 46) bidx = 12;
    else if (ad < 64) bidx = 13;
    else if (ad < 91) bidx = 14;
    else bidx = 15;
    bt[h * 4095 + (delta + 2047)] = (rel_emb[(rb + bidx) * NH + h] - 40.0f) * LOG2E;
}

// ---------------- fused presplit: hidden (hi+lo) and all weights -------------
__global__ __launch_bounds__(256) void presplit_all(
    const float* __restrict__ hidden,
    const float* __restrict__ Wq, const float* __restrict__ Wk,
    const float* __restrict__ Wv, const float* __restrict__ Wo,
    short* __restrict__ Hh, short* __restrict__ Hl,
    short* __restrict__ Wqh, short* __restrict__ Wql,
    short* __restrict__ Wkh, short* __restrict__ Wkl,
    short* __restrict__ Wvh, short* __restrict__ Wvl,
    short* __restrict__ Woh) {
    int idx = blockIdx.x * 256 + threadIdx.x;   // 2,097,152 total
    const float* src;
    short *hi, *lo;
    int loc;
    bool wantLo = true;
    if (idx < 1048576) {
        src = hidden; hi = Hh; lo = Hl; loc = idx;
    } else {
        int j = idx - 1048576;
        int sel = j >> 18;
        loc = j & 0x3FFFF;
        if (sel == 0)      { src = Wq; hi = Wqh; lo = Wql; }
        else if (sel == 1) { src = Wk; hi = Wkh; lo = Wkl; }
        else if (sel == 2) { src = Wv; hi = Wvh; lo = Wvl; }
        else               { src = Wo; hi = Woh; lo = nullptr; wantLo = false; }
    }
    float4 v = ((const float4*)src)[loc];
    const float* p = (const float*)&v;
    sh4 h, l;
#pragma unroll
    for (int j = 0; j < 4; ++j) {
        short hh = f2bf(p[j]);
        h[j] = hh;
        l[j] = f2bf(p[j] - bf2f(hh));
    }
    *(sh4*)&hi[(size_t)loc * 4] = h;
    if (wantLo) *(sh4*)&lo[(size_t)loc * 4] = l;
}

// ---------------- QKV GEMM v9: Q/K bf16x3 compute, plain-bf16 out; V 1-pass --
__global__ __launch_bounds__(256, 3) void qkv_gemm(
    const short* __restrict__ Hh, const short* __restrict__ Hl,
    const short* __restrict__ Wqh, const short* __restrict__ Wql,
    const short* __restrict__ Wkh, const short* __restrict__ Wkl,
    const short* __restrict__ Wvh, const short* __restrict__ Wvl,
    short* __restrict__ Qh, short* __restrict__ Kh, short* __restrict__ Vt) {
    __shared__ short Ah[4096];
    __shared__ short Al[4096];
    __shared__ short Bh[4096];
    __shared__ short Bl[4096];

    int t = threadIdx.x;
    int lane = t & 63, w = t >> 6;
    int wr = w >> 1, wc = w & 1;
    int fr = lane & 15, g = lane >> 4;
    int qrhi = g << 2;

    int lin = blockIdx.y * 24 + blockIdx.x;
    int xcd = lin & 7, i5 = lin >> 3;
    int nb = xcd * 3 + i5 % 3;
    int mb = i5 / 3;

    int proj = (nb * 128) >> 10;
    int nlocal = (nb * 128) & 1023;
    const short* Wh = proj == 0 ? Wqh : (proj == 1 ? Wkh : Wvh);
    const short* Wl = proj == 0 ? Wql : (proj == 1 ? Wkl : Wvl);

    const short* Ahb = Hh + (size_t)(mb * 128) * D_MODEL;
    const short* Alb = Hl + (size_t)(mb * 128) * D_MODEL;
    const short* Bhb = Wh + (size_t)nlocal * D_MODEL;
    const short* Blb = Wl + (size_t)nlocal * D_MODEL;

    fx4 acc[4][4];
#pragma unroll
    for (int i = 0; i < 4; ++i)
#pragma unroll
        for (int j = 0; j < 4; ++j) acc[i][j] = (fx4){0.f, 0.f, 0.f, 0.f};

    auto stage = [&](int kt) {
        int kb = kt * 32;
#pragma unroll
        for (int i = 0; i < 2; ++i) {
            int idx = i * 256 + t;
            int row = idx >> 2;
            int csw = ((idx & 3) ^ (row & 3)) << 3;
            size_t go = (size_t)row * D_MODEL + kb + csw;
            int dst = (i * 256 + w * 64) * 8;
            gl_lds16(Ahb + go, &Ah[dst]);
            gl_lds16(Bhb + go, &Bh[dst]);
            if (proj != 2) {        // V: single-pass, no lo staging
                gl_lds16(Alb + go, &Al[dst]);
                gl_lds16(Blb + go, &Bl[dst]);
            }
        }
    };
    auto compute = [&]() {
        sh8 afh[4], bfh[4];
#pragma unroll
        for (int mi = 0; mi < 4; ++mi) {
            int row = wr * 64 + mi * 16 + fr;
            afh[mi] = *(const sh8*)&Ah[row * 32 + ((g ^ (row & 3)) << 3)];
        }
#pragma unroll
        for (int ni = 0; ni < 4; ++ni) {
            int row = wc * 64 + ni * 16 + fr;
            bfh[ni] = *(const sh8*)&Bh[row * 32 + ((g ^ (row & 3)) << 3)];
        }
#pragma unroll
        for (int mi = 0; mi < 4; ++mi)
#pragma unroll
            for (int ni = 0; ni < 4; ++ni)
                acc[mi][ni] = __builtin_amdgcn_mfma_f32_16x16x32_bf16(afh[mi], bfh[ni], acc[mi][ni], 0, 0, 0);
        if (proj != 2) {
            sh8 afl[4], bfl[4];
#pragma unroll
            for (int mi = 0; mi < 4; ++mi) {
                int row = wr * 64 + mi * 16 + fr;
                afl[mi] = *(const sh8*)&Al[row * 32 + ((g ^ (row & 3)) << 3)];
            }
#pragma unroll
            for (int ni = 0; ni < 4; ++ni) {
                int row = wc * 64 + ni * 16 + fr;
                bfl[ni] = *(const sh8*)&Bl[row * 32 + ((g ^ (row & 3)) << 3)];
            }
#pragma unroll
            for (int mi = 0; mi < 4; ++mi)
#pragma unroll
                for (int ni = 0; ni < 4; ++ni)
                    acc[mi][ni] = __builtin_amdgcn_mfma_f32_16x16x32_bf16(afh[mi], bfl[ni], acc[mi][ni], 0, 0, 0);
#pragma unroll
            for (int mi = 0; mi < 4; ++mi)
#pragma unroll
                for (int ni = 0; ni < 4; ++ni)
                    acc[mi][ni] = __builtin_amdgcn_mfma_f32_16x16x32_bf16(afl[mi], bfh[ni], acc[mi][ni], 0, 0, 0);
        }
    };

#pragma unroll 1
    for (int kt = 0; kt < 32; ++kt) {
        __syncthreads();
        stage(kt);
        __syncthreads();
        compute();
    }

#pragma unroll
    for (int mi = 0; mi < 4; ++mi)
#pragma unroll
        for (int ni = 0; ni < 4; ++ni)
#pragma unroll
            for (int r = 0; r < 4; ++r) {
                int m = mb * 128 + wr * 64 + mi * 16 + qrhi + r;
                int n = nb * 128 + wc * 64 + ni * 16 + fr;
                int nn = n & 1023;
                int h = nn >> 6, d = nn & 63;
                int b = m >> 11, s = m & 2047;
                size_t bh = (size_t)(b * NH + h);
                float val = acc[mi][ni][r];
                if (proj == 0) {
                    Qh[(bh * SEQ + s) * HD + d] = f2bf(val);
                } else if (proj == 1) {
                    Kh[(bh * SEQ + s) * HD + d] = f2bf(val);
                } else {
                    Vt[(bh * HD + d) * SEQ + s] = f2bf(val);
                }
            }
}

// swizzled LDS index (shorts): row-major [64][64], XOR bank swizzle
#define SW(row, scol) (((row) << 6) + ((scol) ^ (((row) & 7) << 3)))

// ---------------- flash attention v11: QK plain bf16, raw v_exp_f32 ----------
__global__ __launch_bounds__(256, 3) void attn_kernel(
    const short* __restrict__ Qhg, const short* __restrict__ Khg,
    const short* __restrict__ Vtg, const float* __restrict__ biasS,
    short* __restrict__ poB, float* __restrict__ plB) {
    __shared__ short Ks[64 * 64];
    __shared__ short Vs[64 * 64];
    __shared__ short Pl[4 * 16 * 72];
    __shared__ float Bt[192];

    int t = threadIdx.x;
    int lane = t & 63, w = t >> 6;
    int fr = lane & 15, g = lane >> 4;
    int fk = g << 3;
    int qrhi = g << 2;
    int qt = blockIdx.x, h = blockIdx.y;
    int b = blockIdx.z >> 1, half = blockIdx.z & 1;
    int qbase = qt * 128;
    int ktbase = half * 16;
    size_t bh = (size_t)(b * NH + h);

    sh8 qh[2][2];
#pragma unroll
    for (int qg = 0; qg < 2; ++qg)
#pragma unroll
        for (int ks = 0; ks < 2; ++ks) {
            int row = qbase + w * 32 + qg * 16 + fr;
            qh[qg][ks] = *(const sh8*)&Qhg[(bh * SEQ + row) * HD + ks * 32 + fk];
        }

    float lrow[2][4];
    fx4 o[2][4];
#pragma unroll
    for (int qg = 0; qg < 2; ++qg) {
#pragma unroll
        for (int r = 0; r < 4; ++r) lrow[qg][r] = 0.f;
#pragma unroll
        for (int di = 0; di < 4; ++di) o[qg][di] = (fx4){0.f, 0.f, 0.f, 0.f};
    }

    // hoisted kt-invariant LDS offsets
    int fo[2][4];
#pragma unroll
    for (int ks = 0; ks < 2; ++ks)
#pragma unroll
        for (int i = 0; i < 4; ++i) fo[ks][i] = SW(i * 16 + fr, ks * 32 + fk);
    int shftw = ((qrhi >> 3) & 1) << 3;
    int shftr = ((fr >> 3) & 1) << 3;
    int pbase = w * 1152;
    int pw = pbase + qrhi * 72 + fr + shftw;
    int pr0 = pbase + fr * 72 + fk + shftr;

    // glds staging: linear dest chunk cd; source chunk = p ^ (row&7)
    int sd[2], srow[2], schunk[2];
#pragma unroll
    for (int i = 0; i < 2; ++i) {
        int cd = i * 256 + t;
        int row = cd >> 3, p = cd & 7;
        sd[i] = cd * 8;
        srow[i] = row;
        schunk[i] = (p ^ (row & 7)) << 3;
    }

    const short* kbase = Khg + bh * SEQ * HD;
    const short* vbase = Vtg + bh * HD * SEQ;

    for (int ktl = 0; ktl < 16; ++ktl) {
        int kt = ktbase + ktl;
        __syncthreads();    // previous iteration's LDS reads complete
#pragma unroll
        for (int i = 0; i < 2; ++i) {
            gl_lds16(kbase + (size_t)(kt * 64 + srow[i]) * HD + schunk[i], &Ks[sd[i]]);
            gl_lds16(vbase + (size_t)srow[i] * SEQ + kt * 64 + schunk[i], &Vs[sd[i]]);
        }
        if (t < 191) Bt[t] = biasS[h * 4095 + 2047 + (kt * 64 - qbase - 127) + t];
        __syncthreads();    // glds + bias landed

        // QK^T (plain bf16: qh * kh)
        fx4 sc[2][4];
#pragma unroll
        for (int qg = 0; qg < 2; ++qg)
#pragma unroll
            for (int ni = 0; ni < 4; ++ni) sc[qg][ni] = (fx4){0.f, 0.f, 0.f, 0.f};
        __builtin_amdgcn_s_setprio(1);
#pragma unroll
        for (int ks = 0; ks < 2; ++ks)
#pragma unroll
            for (int ni = 0; ni < 4; ++ni) {
                sh8 kf = *(const sh8*)&Ks[fo[ks][ni]];
#pragma unroll
                for (int qg = 0; qg < 2; ++qg)
                    sc[qg][ni] = __builtin_amdgcn_mfma_f32_16x16x32_bf16(qh[qg][ks], kf, sc[qg][ni], 0, 0, 0);
            }
        __builtin_amdgcn_s_setprio(0);

        // per-qg: softmax -> P -> PV
#pragma unroll
        for (int qg = 0; qg < 2; ++qg) {
#pragma unroll
            for (int r = 0; r < 4; ++r) {
                int bidx0 = 127 + fr - (w * 32 + qg * 16 + qrhi + r);
                float psum = 0.f;
#pragma unroll
                for (int ni = 0; ni < 4; ++ni) {
                    float p = fexp2(fmaf(sc[qg][ni][r], LOG2E, Bt[bidx0 + ni * 16]));
                    sc[qg][ni][r] = p;
                    psum += p;
                }
                lrow[qg][r] += psum;
#pragma unroll
                for (int ni = 0; ni < 4; ++ni)
                    Pl[pw + r * 72 + ni * 16] = truncbf(sc[qg][ni][r]);
            }
            sh8 pa0 = *(const sh8*)&Pl[pr0];
            sh8 pa1 = *(const sh8*)&Pl[pr0 + 32];
            __builtin_amdgcn_s_setprio(1);
#pragma unroll
            for (int di = 0; di < 4; ++di) {
                sh8 vb0 = *(const sh8*)&Vs[fo[0][di]];
                sh8 vb1 = *(const sh8*)&Vs[fo[1][di]];
                o[qg][di] = __builtin_amdgcn_mfma_f32_16x16x32_bf16(pa0, vb0, o[qg][di], 0, 0, 0);
                o[qg][di] = __builtin_amdgcn_mfma_f32_16x16x32_bf16(pa1, vb1, o[qg][di], 0, 0, 0);
            }
            __builtin_amdgcn_s_setprio(0);
        }
    }

#pragma unroll
    for (int qg = 0; qg < 2; ++qg)
#pragma unroll
        for (int r = 0; r < 4; ++r) {
#pragma unroll
            for (int off = 1; off < 16; off <<= 1)
                lrow[qg][r] += __shfl_xor(lrow[qg][r], off, 64);
        }

    // epilogue: normalized partial O (bf16) + partial l (f32)
    short* po = poB + (size_t)half * (NB * SEQ * (size_t)D_MODEL);
    float* pl = plB + (size_t)half * (NB * NH * SEQ);
#pragma unroll
    for (int qg = 0; qg < 2; ++qg)
#pragma unroll
        for (int di = 0; di < 4; ++di)
#pragma unroll
            for (int r = 0; r < 4; ++r) {
                int q = qbase + w * 32 + qg * 16 + qrhi + r;
                int d = di * 16 + fr;
                po[((size_t)b * SEQ + q) * D_MODEL + h * HD + d] =
                    f2bf(o[qg][di][r] / lrow[qg][r]);
            }
    if (fr == 0) {
#pragma unroll
        for (int qg = 0; qg < 2; ++qg)
#pragma unroll
            for (int r = 0; r < 4; ++r) {
                int q = qbase + w * 32 + qg * 16 + qrhi + r;
                pl[bh * SEQ + q] = lrow[qg][r];
            }
    }
}

// ---------------- combine: ctx = (l0*O0' + l1*O1') / (l0+l1), bf16 -----------
__global__ __launch_bounds__(256) void combine_kernel(
    const short* __restrict__ poB, const float* __restrict__ plB,
    short* __restrict__ ctx) {
    const size_t NEl = (size_t)NB * SEQ * D_MODEL;
    int idx = blockIdx.x * 256 + threadIdx.x;
    if (idx >= (int)(NEl / 8)) return;
    size_t e = (size_t)idx * 8;
    int c = (int)(e & 1023);
    int h = c >> 6;
    int bq = (int)(e >> 10);
    int b = bq >> 11, q = bq & 2047;
    sh8 a0 = *(const sh8*)&poB[e];
    sh8 a1 = *(const sh8*)&poB[NEl + e];
    int li = (b * NH + h) * SEQ + q;
    float l0 = plB[li];
    float l1 = plB[NB * NH * SEQ + li];
    float inv = 1.0f / (l0 + l1);
    float w0 = l0 * inv, w1 = l1 * inv;
    sh8 r;
#pragma unroll
    for (int j = 0; j < 8; ++j)
        r[j] = f2bf(bf2f(a0[j]) * w0 + bf2f(a1[j]) * w1);
    *(sh8*)&ctx[e] = r;
}

// ---------------- output projection: 64x128 tile, dbuf, gload_lds ------------
__global__ __launch_bounds__(256) void o_gemm(
    const short* __restrict__ Actx, const short* __restrict__ Woh,
    float* __restrict__ out) {
    __shared__ short Ab[2][2048];
    __shared__ short Bb[2][4096];

    int t = threadIdx.x;
    int lane = t & 63, w = t >> 6;
    int wr = w >> 1, wc = w & 1;
    int fr = lane & 15, g = lane >> 4;
    int qrhi = g << 2;

    int lin = blockIdx.y * 8 + blockIdx.x;      // 512 blocks
    int swz = (lin & 7) * 64 + (lin >> 3);
    int nb = swz & 7, mb = swz >> 3;

    fx4 acc[2][4];
#pragma unroll
    for (int i = 0; i < 2; ++i)
#pragma unroll
        for (int j = 0; j < 4; ++j) acc[i][j] = (fx4){0.f, 0.f, 0.f, 0.f};

    int row0 = t >> 2, c0 = t & 3;

    auto stage = [&](int kt, int buf) {
        int kb = kt * 32;
        {
            int row = row0;
            int csw = (c0 ^ (row & 3)) << 3;
            gl_lds16(&Actx[(size_t)(mb * 64 + row) * D_MODEL + kb + csw],
                     &Ab[buf][(w * 64) * 8]);
        }
#pragma unroll
        for (int i = 0; i < 2; ++i) {
            int row = row0 + i * 64;
            int csw = (c0 ^ (row & 3)) << 3;
            gl_lds16(&Woh[(size_t)(nb * 128 + row) * D_MODEL + kb + csw],
                     &Bb[buf][(i * 256 + w * 64) * 8]);
        }
    };
    auto compute = [&](int buf) {
        sh8 af[2], bf[4];
#pragma unroll
        for (int mi = 0; mi < 2; ++mi) {
            int row = wr * 32 + mi * 16 + fr;
            af[mi] = *(const sh8*)&Ab[buf][(row << 5) + ((g ^ (row & 3)) << 3)];
        }
#pragma unroll
        for (int ni = 0; ni < 4; ++ni) {
            int row = wc * 64 + ni * 16 + fr;
            bf[ni] = *(const sh8*)&Bb[buf][(row << 5) + ((g ^ (row & 3)) << 3)];
        }
#pragma unroll
        for (int mi = 0; mi < 2; ++mi)
#pragma unroll
            for (int ni = 0; ni < 4; ++ni)
                acc[mi][ni] = __builtin_amdgcn_mfma_f32_16x16x32_bf16(af[mi], bf[ni], acc[mi][ni], 0, 0, 0);
    };

    stage(0, 0);
    asm volatile("s_waitcnt vmcnt(0)" ::: "memory");
    __builtin_amdgcn_s_barrier();

    int cur = 0;
#pragma unroll 1
    for (int kt = 0; kt < 31; ++kt) {
        stage(kt + 1, cur ^ 1);
        compute(cur);
        asm volatile("s_waitcnt vmcnt(0)" ::: "memory");
        __builtin_amdgcn_s_barrier();
        cur ^= 1;
    }
    compute(cur);

#pragma unroll
    for (int mi = 0; mi < 2; ++mi)
#pragma unroll
        for (int ni = 0; ni < 4; ++ni)
#pragma unroll
            for (int r = 0; r < 4; ++r) {
                int m = mb * 64 + wr * 32 + mi * 16 + qrhi + r;
                int n = nb * 128 + wc * 64 + ni * 16 + fr;
                out[(size_t)m * D_MODEL + n] = acc[mi][ni][r];
            }
}

extern "C" void kernel_launch(void* const* d_in, const int* in_sizes, int n_in,
                              void* d_out, int out_size, void* d_ws, size_t ws_size,
                              hipStream_t stream) {
    const float* hidden = (const float*)d_in[0];
    const float* Wq = (const float*)d_in[1];
    const float* Wk = (const float*)d_in[2];
    const float* Wv = (const float*)d_in[3];
    const float* Wo = (const float*)d_in[4];
    const float* rel = (const float*)d_in[5];
    float* out = (float*)d_out;

    const size_t NE = (size_t)NB * NH * SEQ * HD;   // 4,194,304 (x2B = 8MB)
    const size_t WE = (size_t)D_MODEL * D_MODEL;    // 1,048,576 (x2B = 2MB)
    char* ws = (char*)d_ws;
    short* Qh = (short*)(ws + 0 * NE * 2);
    short* Kh = (short*)(ws + 2 * NE * 2);
    short* Vt = (short*)(ws + 4 * NE * 2);          // [32,40)MB; dead after attn
    char* wsp = ws + 5 * NE * 2;                    // 40MB mark
    short* Wqh = (short*)(wsp + 0 * WE * 2);
    short* Wql = (short*)(wsp + 1 * WE * 2);
    short* Wkh = (short*)(wsp + 2 * WE * 2);
    short* Wkl = (short*)(wsp + 3 * WE * 2);
    short* Wvh = (short*)(wsp + 4 * WE * 2);
    short* Wvl = (short*)(wsp + 5 * WE * 2);
    short* Woh = (short*)(wsp + 6 * WE * 2);        // survives until o_gemm
    float* bias = (float*)(wsp + 7 * WE * 2);       // 54MB mark, 256KB
    float* plB = (float*)(wsp + 7 * WE * 2 + 262144);  // 512KB partial l
    short* ctxb = Vt;   // alias: Vt dead after attn; combine writes here

    // Hh/Hl then partial-O both live in d_out (16MB), phase-disjoint.
    short* Hh = (short*)d_out;
    short* Hl = Hh + NE;
    short* poB = (short*)d_out;

    bias_kernel<<<dim3(256), dim3(256), 0, stream>>>(rel, bias);
    presplit_all<<<dim3(8192), dim3(256), 0, stream>>>(
        hidden, Wq, Wk, Wv, Wo, Hh, Hl, Wqh, Wql, Wkh, Wkl, Wvh, Wvl, Woh);
    qkv_gemm<<<dim3(24, 32), dim3(256), 0, stream>>>(
        Hh, Hl, Wqh, Wql, Wkh, Wkl, Wvh, Wvl, Qh, Kh, Vt);
    attn_kernel<<<dim3(16, 16, 4), dim3(256), 0, stream>>>(
        Qh, Kh, Vt, bias, poB, plB);
    combine_kernel<<<dim3(2048), dim3(256), 0, stream>>>(poB, plB, ctxb);
    o_gemm<<<dim3(8, 64), dim3(256), 0, stream>>>(ctxb, Woh, out);
}

// Round 20
// 165.532 us; speedup vs baseline: 1.6820x; 1.0997x over previous
//
#include <hip/hip_runtime.h>
#include <hip/hip_bf16.h>

#define D_MODEL 1024
#define NH 16
#define HD 64
#define SEQ 2048
#define NB 2
#define LOG2E 1.4426950408889634f

typedef __attribute__((ext_vector_type(8))) short sh8;
typedef __attribute__((ext_vector_type(4))) short sh4;
typedef __attribute__((ext_vector_type(4))) float fx4;

__device__ __forceinline__ short f2bf(float x) {
    union { float f; unsigned u; } v; v.f = x;
    unsigned r = (v.u + 0x7FFFu + ((v.u >> 16) & 1u)) >> 16;
    return (short)r;
}
__device__ __forceinline__ float bf2f(short b) {
    union { float f; unsigned u; } v; v.u = ((unsigned)(unsigned short)b) << 16;
    return v.f;
}
__device__ __forceinline__ short truncbf(float x) {
    union { float f; unsigned u; } v; v.f = x;
    return (short)(v.u >> 16);
}
// bare v_exp_f32: args bounded above; deep-negative flushes to 0 (desired)
__device__ __forceinline__ float fexp2(float x) {
    float r;
    asm("v_exp_f32 %0, %1" : "=v"(r) : "v"(x));
    return r;
}

// async global->LDS, 16B per lane. LDS dest linear: wave base + lane*16.
__device__ __forceinline__ void gl_lds16(const short* g, short* l) {
    __builtin_amdgcn_global_load_lds(
        (const __attribute__((address_space(1))) void*)(uintptr_t)(const void*)g,
        (__attribute__((address_space(3))) void*)(uintptr_t)(void*)l, 16, 0, 0);
}

// ---------------- bias table: bt[h][delta+2047] = (bias - 40) * log2(e) ------
__global__ __launch_bounds__(256) void bias_kernel(const float* __restrict__ rel_emb,
                                                   float* __restrict__ bt) {
    int i = blockIdx.x * 256 + threadIdx.x;
    if (i >= NH * 4095) return;
    int h = i / 4095;
    int delta = (i % 4095) - 2047;
    int rb = delta > 0 ? 16 : 0;
    int ad = delta < 0 ? -delta : delta;
    int bidx;
    if (ad < 8) bidx = ad;
    else if (ad < 12) bidx = 8;
    else if (ad < 16) bidx = 9;
    else if (ad < 23) bidx = 10;
    else if (ad < 32) bidx = 11;
    else if (ad < 46) bidx = 12;
    else if (ad < 64) bidx = 13;
    else if (ad < 91) bidx = 14;
    else bidx = 15;
    bt[h * 4095 + (delta + 2047)] = (rel_emb[(rb + bidx) * NH + h] - 40.0f) * LOG2E;
}

// ---------------- presplit hidden (hi+lo) + cvt weights (hi only) ------------
__global__ __launch_bounds__(256) void presplit_h_cvt_w(
    const float* __restrict__ hidden,
    const float* __restrict__ Wq, const float* __restrict__ Wk,
    const float* __restrict__ Wv, const float* __restrict__ Wo,
    short* __restrict__ Hh, short* __restrict__ Hl,
    short* __restrict__ Wqh, short* __restrict__ Wkh,
    short* __restrict__ Wvh, short* __restrict__ Woh) {
    int idx = blockIdx.x * 256 + threadIdx.x;   // 2,097,152 total float4 jobs
    if (idx < 1048576) {                         // hidden: hi + lo
        float4 v = ((const float4*)hidden)[idx];
        const float* p = (const float*)&v;
        sh4 h, l;
#pragma unroll
        for (int j = 0; j < 4; ++j) {
            short hh = f2bf(p[j]);
            h[j] = hh;
            l[j] = f2bf(p[j] - bf2f(hh));
        }
        *(sh4*)&Hh[(size_t)idx * 4] = h;
        *(sh4*)&Hl[(size_t)idx * 4] = l;
    } else {                                     // weights: hi only
        int j = idx - 1048576;
        int sel = j >> 18;
        int loc = j & 0x3FFFF;
        const float* src;
        short* dst;
        if (sel == 0)      { src = Wq; dst = Wqh; }
        else if (sel == 1) { src = Wk; dst = Wkh; }
        else if (sel == 2) { src = Wv; dst = Wvh; }
        else               { src = Wo; dst = Woh; }
        float4 v = ((const float4*)src)[loc];
        const float* p = (const float*)&v;
        sh4 h;
#pragma unroll
        for (int jj = 0; jj < 4; ++jj) h[jj] = f2bf(p[jj]);
        *(sh4*)&dst[(size_t)loc * 4] = h;
    }
}

// ---------------- QKV GEMM v11: Q/K bf16x2 (Ah+Al)*Bh, V single-pass ---------
__global__ __launch_bounds__(256, 3) void qkv_gemm(
    const short* __restrict__ Hh, const short* __restrict__ Hl,
    const short* __restrict__ Wqh, const short* __restrict__ Wkh,
    const short* __restrict__ Wvh,
    short* __restrict__ Qh, short* __restrict__ Kh, short* __restrict__ Vt) {
    __shared__ short Ah[4096];
    __shared__ short Al[4096];
    __shared__ short Bh[4096];

    int t = threadIdx.x;
    int lane = t & 63, w = t >> 6;
    int wr = w >> 1, wc = w & 1;
    int fr = lane & 15, g = lane >> 4;
    int qrhi = g << 2;

    int lin = blockIdx.y * 24 + blockIdx.x;
    int xcd = lin & 7, i5 = lin >> 3;
    int nb = xcd * 3 + i5 % 3;
    int mb = i5 / 3;

    int proj = (nb * 128) >> 10;
    int nlocal = (nb * 128) & 1023;
    const short* Wh = proj == 0 ? Wqh : (proj == 1 ? Wkh : Wvh);

    const short* Ahb = Hh + (size_t)(mb * 128) * D_MODEL;
    const short* Alb = Hl + (size_t)(mb * 128) * D_MODEL;
    const short* Bhb = Wh + (size_t)nlocal * D_MODEL;

    fx4 acc[4][4];
#pragma unroll
    for (int i = 0; i < 4; ++i)
#pragma unroll
        for (int j = 0; j < 4; ++j) acc[i][j] = (fx4){0.f, 0.f, 0.f, 0.f};

    auto stage = [&](int kt) {
        int kb = kt * 32;
#pragma unroll
        for (int i = 0; i < 2; ++i) {
            int idx = i * 256 + t;
            int row = idx >> 2;
            int csw = ((idx & 3) ^ (row & 3)) << 3;
            size_t go = (size_t)row * D_MODEL + kb + csw;
            int dst = (i * 256 + w * 64) * 8;
            gl_lds16(Ahb + go, &Ah[dst]);
            gl_lds16(Bhb + go, &Bh[dst]);
            if (proj != 2) gl_lds16(Alb + go, &Al[dst]);   // Q/K: hidden-lo pass
        }
    };
    auto compute = [&]() {
        sh8 afh[4], bfh[4];
#pragma unroll
        for (int mi = 0; mi < 4; ++mi) {
            int row = wr * 64 + mi * 16 + fr;
            afh[mi] = *(const sh8*)&Ah[row * 32 + ((g ^ (row & 3)) << 3)];
        }
#pragma unroll
        for (int ni = 0; ni < 4; ++ni) {
            int row = wc * 64 + ni * 16 + fr;
            bfh[ni] = *(const sh8*)&Bh[row * 32 + ((g ^ (row & 3)) << 3)];
        }
#pragma unroll
        for (int mi = 0; mi < 4; ++mi)
#pragma unroll
            for (int ni = 0; ni < 4; ++ni)
                acc[mi][ni] = __builtin_amdgcn_mfma_f32_16x16x32_bf16(afh[mi], bfh[ni], acc[mi][ni], 0, 0, 0);
        if (proj != 2) {
            sh8 afl[4];
#pragma unroll
            for (int mi = 0; mi < 4; ++mi) {
                int row = wr * 64 + mi * 16 + fr;
                afl[mi] = *(const sh8*)&Al[row * 32 + ((g ^ (row & 3)) << 3)];
            }
#pragma unroll
            for (int mi = 0; mi < 4; ++mi)
#pragma unroll
                for (int ni = 0; ni < 4; ++ni)
                    acc[mi][ni] = __builtin_amdgcn_mfma_f32_16x16x32_bf16(afl[mi], bfh[ni], acc[mi][ni], 0, 0, 0);
        }
    };

#pragma unroll 1
    for (int kt = 0; kt < 32; ++kt) {
        __syncthreads();
        stage(kt);
        __syncthreads();
        compute();
    }

#pragma unroll
    for (int mi = 0; mi < 4; ++mi)
#pragma unroll
        for (int ni = 0; ni < 4; ++ni)
#pragma unroll
            for (int r = 0; r < 4; ++r) {
                int m = mb * 128 + wr * 64 + mi * 16 + qrhi + r;
                int n = nb * 128 + wc * 64 + ni * 16 + fr;
                int nn = n & 1023;
                int h = nn >> 6, d = nn & 63;
                int b = m >> 11, s = m & 2047;
                size_t bh = (size_t)(b * NH + h);
                float val = acc[mi][ni][r];
                if (proj == 0) {
                    Qh[(bh * SEQ + s) * HD + d] = f2bf(val);
                } else if (proj == 1) {
                    Kh[(bh * SEQ + s) * HD + d] = f2bf(val);
                } else {
                    Vt[(bh * HD + d) * SEQ + s] = f2bf(val);
                }
            }
}

// swizzled LDS index (shorts): row-major [64][64], XOR bank swizzle
#define SW(row, scol) (((row) << 6) + ((scol) ^ (((row) & 7) << 3)))

// ---------------- flash attention v11: QK plain bf16, raw v_exp_f32 ----------
__global__ __launch_bounds__(256, 3) void attn_kernel(
    const short* __restrict__ Qhg, const short* __restrict__ Khg,
    const short* __restrict__ Vtg, const float* __restrict__ biasS,
    short* __restrict__ poB, float* __restrict__ plB) {
    __shared__ short Ks[64 * 64];
    __shared__ short Vs[64 * 64];
    __shared__ short Pl[4 * 16 * 72];
    __shared__ float Bt[192];

    int t = threadIdx.x;
    int lane = t & 63, w = t >> 6;
    int fr = lane & 15, g = lane >> 4;
    int fk = g << 3;
    int qrhi = g << 2;
    int qt = blockIdx.x, h = blockIdx.y;
    int b = blockIdx.z >> 1, half = blockIdx.z & 1;
    int qbase = qt * 128;
    int ktbase = half * 16;
    size_t bh = (size_t)(b * NH + h);

    sh8 qh[2][2];
#pragma unroll
    for (int qg = 0; qg < 2; ++qg)
#pragma unroll
        for (int ks = 0; ks < 2; ++ks) {
            int row = qbase + w * 32 + qg * 16 + fr;
            qh[qg][ks] = *(const sh8*)&Qhg[(bh * SEQ + row) * HD + ks * 32 + fk];
        }

    float lrow[2][4];
    fx4 o[2][4];
#pragma unroll
    for (int qg = 0; qg < 2; ++qg) {
#pragma unroll
        for (int r = 0; r < 4; ++r) lrow[qg][r] = 0.f;
#pragma unroll
        for (int di = 0; di < 4; ++di) o[qg][di] = (fx4){0.f, 0.f, 0.f, 0.f};
    }

    // hoisted kt-invariant LDS offsets
    int fo[2][4];
#pragma unroll
    for (int ks = 0; ks < 2; ++ks)
#pragma unroll
        for (int i = 0; i < 4; ++i) fo[ks][i] = SW(i * 16 + fr, ks * 32 + fk);
    int shftw = ((qrhi >> 3) & 1) << 3;
    int shftr = ((fr >> 3) & 1) << 3;
    int pbase = w * 1152;
    int pw = pbase + qrhi * 72 + fr + shftw;
    int pr0 = pbase + fr * 72 + fk + shftr;

    // glds staging: linear dest chunk cd; source chunk = p ^ (row&7)
    int sd[2], srow[2], schunk[2];
#pragma unroll
    for (int i = 0; i < 2; ++i) {
        int cd = i * 256 + t;
        int row = cd >> 3, p = cd & 7;
        sd[i] = cd * 8;
        srow[i] = row;
        schunk[i] = (p ^ (row & 7)) << 3;
    }

    const short* kbase = Khg + bh * SEQ * HD;
    const short* vbase = Vtg + bh * HD * SEQ;

    for (int ktl = 0; ktl < 16; ++ktl) {
        int kt = ktbase + ktl;
        __syncthreads();    // previous iteration's LDS reads complete
#pragma unroll
        for (int i = 0; i < 2; ++i) {
            gl_lds16(kbase + (size_t)(kt * 64 + srow[i]) * HD + schunk[i], &Ks[sd[i]]);
            gl_lds16(vbase + (size_t)srow[i] * SEQ + kt * 64 + schunk[i], &Vs[sd[i]]);
        }
        if (t < 191) Bt[t] = biasS[h * 4095 + 2047 + (kt * 64 - qbase - 127) + t];
        __syncthreads();    // glds + bias landed

        // QK^T (plain bf16: qh * kh)
        fx4 sc[2][4];
#pragma unroll
        for (int qg = 0; qg < 2; ++qg)
#pragma unroll
            for (int ni = 0; ni < 4; ++ni) sc[qg][ni] = (fx4){0.f, 0.f, 0.f, 0.f};
        __builtin_amdgcn_s_setprio(1);
#pragma unroll
        for (int ks = 0; ks < 2; ++ks)
#pragma unroll
            for (int ni = 0; ni < 4; ++ni) {
                sh8 kf = *(const sh8*)&Ks[fo[ks][ni]];
#pragma unroll
                for (int qg = 0; qg < 2; ++qg)
                    sc[qg][ni] = __builtin_amdgcn_mfma_f32_16x16x32_bf16(qh[qg][ks], kf, sc[qg][ni], 0, 0, 0);
            }
        __builtin_amdgcn_s_setprio(0);

        // per-qg: softmax -> P -> PV
#pragma unroll
        for (int qg = 0; qg < 2; ++qg) {
#pragma unroll
            for (int r = 0; r < 4; ++r) {
                int bidx0 = 127 + fr - (w * 32 + qg * 16 + qrhi + r);
                float psum = 0.f;
#pragma unroll
                for (int ni = 0; ni < 4; ++ni) {
                    float p = fexp2(fmaf(sc[qg][ni][r], LOG2E, Bt[bidx0 + ni * 16]));
                    sc[qg][ni][r] = p;
                    psum += p;
                }
                lrow[qg][r] += psum;
#pragma unroll
                for (int ni = 0; ni < 4; ++ni)
                    Pl[pw + r * 72 + ni * 16] = truncbf(sc[qg][ni][r]);
            }
            sh8 pa0 = *(const sh8*)&Pl[pr0];
            sh8 pa1 = *(const sh8*)&Pl[pr0 + 32];
            __builtin_amdgcn_s_setprio(1);
#pragma unroll
            for (int di = 0; di < 4; ++di) {
                sh8 vb0 = *(const sh8*)&Vs[fo[0][di]];
                sh8 vb1 = *(const sh8*)&Vs[fo[1][di]];
                o[qg][di] = __builtin_amdgcn_mfma_f32_16x16x32_bf16(pa0, vb0, o[qg][di], 0, 0, 0);
                o[qg][di] = __builtin_amdgcn_mfma_f32_16x16x32_bf16(pa1, vb1, o[qg][di], 0, 0, 0);
            }
            __builtin_amdgcn_s_setprio(0);
        }
    }

#pragma unroll
    for (int qg = 0; qg < 2; ++qg)
#pragma unroll
        for (int r = 0; r < 4; ++r) {
#pragma unroll
            for (int off = 1; off < 16; off <<= 1)
                lrow[qg][r] += __shfl_xor(lrow[qg][r], off, 64);
        }

    // epilogue: normalized partial O (bf16) + partial l (f32)
    short* po = poB + (size_t)half * (NB * SEQ * (size_t)D_MODEL);
    float* pl = plB + (size_t)half * (NB * NH * SEQ);
#pragma unroll
    for (int qg = 0; qg < 2; ++qg)
#pragma unroll
        for (int di = 0; di < 4; ++di)
#pragma unroll
            for (int r = 0; r < 4; ++r) {
                int q = qbase + w * 32 + qg * 16 + qrhi + r;
                int d = di * 16 + fr;
                po[((size_t)b * SEQ + q) * D_MODEL + h * HD + d] =
                    f2bf(o[qg][di][r] / lrow[qg][r]);
            }
    if (fr == 0) {
#pragma unroll
        for (int qg = 0; qg < 2; ++qg)
#pragma unroll
            for (int r = 0; r < 4; ++r) {
                int q = qbase + w * 32 + qg * 16 + qrhi + r;
                pl[bh * SEQ + q] = lrow[qg][r];
            }
    }
}

// ---------------- combine: ctx = (l0*O0' + l1*O1') / (l0+l1), bf16 -----------
__global__ __launch_bounds__(256) void combine_kernel(
    const short* __restrict__ poB, const float* __restrict__ plB,
    short* __restrict__ ctx) {
    const size_t NEl = (size_t)NB * SEQ * D_MODEL;
    int idx = blockIdx.x * 256 + threadIdx.x;
    if (idx >= (int)(NEl / 8)) return;
    size_t e = (size_t)idx * 8;
    int c = (int)(e & 1023);
    int h = c >> 6;
    int bq = (int)(e >> 10);
    int b = bq >> 11, q = bq & 2047;
    sh8 a0 = *(const sh8*)&poB[e];
    sh8 a1 = *(const sh8*)&poB[NEl + e];
    int li = (b * NH + h) * SEQ + q;
    float l0 = plB[li];
    float l1 = plB[NB * NH * SEQ + li];
    float inv = 1.0f / (l0 + l1);
    float w0 = l0 * inv, w1 = l1 * inv;
    sh8 r;
#pragma unroll
    for (int j = 0; j < 8; ++j)
        r[j] = f2bf(bf2f(a0[j]) * w0 + bf2f(a1[j]) * w1);
    *(sh8*)&ctx[e] = r;
}

// ---------------- output projection: 64x128 tile, dbuf, gload_lds ------------
__global__ __launch_bounds__(256) void o_gemm(
    const short* __restrict__ Actx, const short* __restrict__ Woh,
    float* __restrict__ out) {
    __shared__ short Ab[2][2048];
    __shared__ short Bb[2][4096];

    int t = threadIdx.x;
    int lane = t & 63, w = t >> 6;
    int wr = w >> 1, wc = w & 1;
    int fr = lane & 15, g = lane >> 4;
    int qrhi = g << 2;

    int lin = blockIdx.y * 8 + blockIdx.x;      // 512 blocks
    int swz = (lin & 7) * 64 + (lin >> 3);
    int nb = swz & 7, mb = swz >> 3;

    fx4 acc[2][4];
#pragma unroll
    for (int i = 0; i < 2; ++i)
#pragma unroll
        for (int j = 0; j < 4; ++j) acc[i][j] = (fx4){0.f, 0.f, 0.f, 0.f};

    int row0 = t >> 2, c0 = t & 3;

    auto stage = [&](int kt, int buf) {
        int kb = kt * 32;
        {
            int row = row0;
            int csw = (c0 ^ (row & 3)) << 3;
            gl_lds16(&Actx[(size_t)(mb * 64 + row) * D_MODEL + kb + csw],
                     &Ab[buf][(w * 64) * 8]);
        }
#pragma unroll
        for (int i = 0; i < 2; ++i) {
            int row = row0 + i * 64;
            int csw = (c0 ^ (row & 3)) << 3;
            gl_lds16(&Woh[(size_t)(nb * 128 + row) * D_MODEL + kb + csw],
                     &Bb[buf][(i * 256 + w * 64) * 8]);
        }
    };
    auto compute = [&](int buf) {
        sh8 af[2], bf[4];
#pragma unroll
        for (int mi = 0; mi < 2; ++mi) {
            int row = wr * 32 + mi * 16 + fr;
            af[mi] = *(const sh8*)&Ab[buf][(row << 5) + ((g ^ (row & 3)) << 3)];
        }
#pragma unroll
        for (int ni = 0; ni < 4; ++ni) {
            int row = wc * 64 + ni * 16 + fr;
            bf[ni] = *(const sh8*)&Bb[buf][(row << 5) + ((g ^ (row & 3)) << 3)];
        }
#pragma unroll
        for (int mi = 0; mi < 2; ++mi)
#pragma unroll
            for (int ni = 0; ni < 4; ++ni)
                acc[mi][ni] = __builtin_amdgcn_mfma_f32_16x16x32_bf16(af[mi], bf[ni], acc[mi][ni], 0, 0, 0);
    };

    stage(0, 0);
    asm volatile("s_waitcnt vmcnt(0)" ::: "memory");
    __builtin_amdgcn_s_barrier();

    int cur = 0;
#pragma unroll 1
    for (int kt = 0; kt < 31; ++kt) {
        stage(kt + 1, cur ^ 1);
        compute(cur);
        asm volatile("s_waitcnt vmcnt(0)" ::: "memory");
        __builtin_amdgcn_s_barrier();
        cur ^= 1;
    }
    compute(cur);

#pragma unroll
    for (int mi = 0; mi < 2; ++mi)
#pragma unroll
        for (int ni = 0; ni < 4; ++ni)
#pragma unroll
            for (int r = 0; r < 4; ++r) {
                int m = mb * 64 + wr * 32 + mi * 16 + qrhi + r;
                int n = nb * 128 + wc * 64 + ni * 16 + fr;
                out[(size_t)m * D_MODEL + n] = acc[mi][ni][r];
            }
}

extern "C" void kernel_launch(void* const* d_in, const int* in_sizes, int n_in,
                              void* d_out, int out_size, void* d_ws, size_t ws_size,
                              hipStream_t stream) {
    const float* hidden = (const float*)d_in[0];
    const float* Wq = (const float*)d_in[1];
    const float* Wk = (const float*)d_in[2];
    const float* Wv = (const float*)d_in[3];
    const float* Wo = (const float*)d_in[4];
    const float* rel = (const float*)d_in[5];
    float* out = (float*)d_out;

    const size_t NE = (size_t)NB * NH * SEQ * HD;   // 4,194,304 (x2B = 8MB)
    const size_t WE = (size_t)D_MODEL * D_MODEL;    // 1,048,576 (x2B = 2MB)
    char* ws = (char*)d_ws;
    short* Qh = (short*)(ws + 0 * NE * 2);
    short* Kh = (short*)(ws + 2 * NE * 2);
    short* Vt = (short*)(ws + 4 * NE * 2);          // [32,40)MB; dead after attn
    char* wsp = ws + 5 * NE * 2;                    // 40MB mark
    short* Wqh = (short*)(wsp + 0 * WE * 2);
    short* Wkh = (short*)(wsp + 2 * WE * 2);
    short* Wvh = (short*)(wsp + 4 * WE * 2);
    short* Woh = (short*)(wsp + 6 * WE * 2);        // survives until o_gemm
    float* bias = (float*)(wsp + 7 * WE * 2);       // 54MB mark, 256KB
    float* plB = (float*)(wsp + 7 * WE * 2 + 262144);  // 512KB partial l
    short* ctxb = Vt;   // alias: Vt dead after attn; combine writes here

    // Hh/Hl then partial-O both live in d_out (16MB), phase-disjoint.
    short* Hh = (short*)d_out;
    short* Hl = Hh + NE;
    short* poB = (short*)d_out;

    bias_kernel<<<dim3(256), dim3(256), 0, stream>>>(rel, bias);
    presplit_h_cvt_w<<<dim3(8192), dim3(256), 0, stream>>>(
        hidden, Wq, Wk, Wv, Wo, Hh, Hl, Wqh, Wkh, Wvh, Woh);
    qkv_gemm<<<dim3(24, 32), dim3(256), 0, stream>>>(
        Hh, Hl, Wqh, Wkh, Wvh, Qh, Kh, Vt);
    attn_kernel<<<dim3(16, 16, 4), dim3(256), 0, stream>>>(
        Qh, Kh, Vt, bias, poB, plB);
    combine_kernel<<<dim3(2048), dim3(256), 0, stream>>>(poB, plB, ctxb);
    o_gemm<<<dim3(8, 64), dim3(256), 0, stream>>>(ctxb, Woh, out);
}

// Round 21
// 161.462 us; speedup vs baseline: 1.7244x; 1.0252x over previous
//
#include <hip/hip_runtime.h>
#include <hip/hip_bf16.h>

#define D_MODEL 1024
#define NH 16
#define HD 64
#define SEQ 2048
#define NB 2
#define LOG2E 1.4426950408889634f

typedef __attribute__((ext_vector_type(8))) short sh8;
typedef __attribute__((ext_vector_type(4))) short sh4;
typedef __attribute__((ext_vector_type(4))) float fx4;

__device__ __forceinline__ short f2bf(float x) {
    union { float f; unsigned u; } v; v.f = x;
    unsigned r = (v.u + 0x7FFFu + ((v.u >> 16) & 1u)) >> 16;
    return (short)r;
}
__device__ __forceinline__ float bf2f(short b) {
    union { float f; unsigned u; } v; v.u = ((unsigned)(unsigned short)b) << 16;
    return v.f;
}
__device__ __forceinline__ short truncbf(float x) {
    union { float f; unsigned u; } v; v.f = x;
    return (short)(v.u >> 16);
}
// bare v_exp_f32: args bounded above; deep-negative flushes to 0 (desired)
__device__ __forceinline__ float fexp2(float x) {
    float r;
    asm("v_exp_f32 %0, %1" : "=v"(r) : "v"(x));
    return r;
}

// async global->LDS, 16B per lane. LDS dest linear: wave base + lane*16.
__device__ __forceinline__ void gl_lds16(const short* g, short* l) {
    __builtin_amdgcn_global_load_lds(
        (const __attribute__((address_space(1))) void*)(uintptr_t)(const void*)g,
        (__attribute__((address_space(3))) void*)(uintptr_t)(void*)l, 16, 0, 0);
}

// ---------------- bias table: bt[h][delta+2047] = (bias - 40) * log2(e) ------
__global__ __launch_bounds__(256) void bias_kernel(const float* __restrict__ rel_emb,
                                                   float* __restrict__ bt) {
    int i = blockIdx.x * 256 + threadIdx.x;
    if (i >= NH * 4095) return;
    int h = i / 4095;
    int delta = (i % 4095) - 2047;
    int rb = delta > 0 ? 16 : 0;
    int ad = delta < 0 ? -delta : delta;
    int bidx;
    if (ad < 8) bidx = ad;
    else if (ad < 12) bidx = 8;
    else if (ad < 16) bidx = 9;
    else if (ad < 23) bidx = 10;
    else if (ad < 32) bidx = 11;
    else if (ad < 46) bidx = 12;
    else if (ad < 64) bidx = 13;
    else if (ad < 91) bidx = 14;
    else bidx = 15;
    bt[h * 4095 + (delta + 2047)] = (rel_emb[(rb + bidx) * NH + h] - 40.0f) * LOG2E;
}

// ---------------- presplit hidden (hi+lo) + cvt weights (hi only) ------------
__global__ __launch_bounds__(256) void presplit_h_cvt_w(
    const float* __restrict__ hidden,
    const float* __restrict__ Wq, const float* __restrict__ Wk,
    const float* __restrict__ Wv, const float* __restrict__ Wo,
    short* __restrict__ Hh, short* __restrict__ Hl,
    short* __restrict__ Wqh, short* __restrict__ Wkh,
    short* __restrict__ Wvh, short* __restrict__ Woh) {
    int idx = blockIdx.x * 256 + threadIdx.x;   // 2,097,152 total float4 jobs
    if (idx < 1048576) {                         // hidden: hi + lo
        float4 v = ((const float4*)hidden)[idx];
        const float* p = (const float*)&v;
        sh4 h, l;
#pragma unroll
        for (int j = 0; j < 4; ++j) {
            short hh = f2bf(p[j]);
            h[j] = hh;
            l[j] = f2bf(p[j] - bf2f(hh));
        }
        *(sh4*)&Hh[(size_t)idx * 4] = h;
        *(sh4*)&Hl[(size_t)idx * 4] = l;
    } else {                                     // weights: hi only
        int j = idx - 1048576;
        int sel = j >> 18;
        int loc = j & 0x3FFFF;
        const float* src;
        short* dst;
        if (sel == 0)      { src = Wq; dst = Wqh; }
        else if (sel == 1) { src = Wk; dst = Wkh; }
        else if (sel == 2) { src = Wv; dst = Wvh; }
        else               { src = Wo; dst = Woh; }
        float4 v = ((const float4*)src)[loc];
        const float* p = (const float*)&v;
        sh4 h;
#pragma unroll
        for (int jj = 0; jj < 4; ++jj) h[jj] = f2bf(p[jj]);
        *(sh4*)&dst[(size_t)loc * 4] = h;
    }
}

// ---------------- QKV GEMM v12: BK=64, Q/K bf16x2, V single-pass -------------
// LDS [128][64] shorts per array; chunk swizzle c^(row&7); 16 K-steps.
__global__ __launch_bounds__(256, 3) void qkv_gemm(
    const short* __restrict__ Hh, const short* __restrict__ Hl,
    const short* __restrict__ Wqh, const short* __restrict__ Wkh,
    const short* __restrict__ Wvh,
    short* __restrict__ Qh, short* __restrict__ Kh, short* __restrict__ Vt) {
    __shared__ short Ah[8192];
    __shared__ short Al[8192];
    __shared__ short Bh[8192];

    int t = threadIdx.x;
    int lane = t & 63, w = t >> 6;
    int wr = w >> 1, wc = w & 1;
    int fr = lane & 15, g = lane >> 4;
    int qrhi = g << 2;

    int lin = blockIdx.y * 24 + blockIdx.x;
    int xcd = lin & 7, i5 = lin >> 3;
    int nb = xcd * 3 + i5 % 3;
    int mb = i5 / 3;

    int proj = (nb * 128) >> 10;
    int nlocal = (nb * 128) & 1023;
    const short* Wh = proj == 0 ? Wqh : (proj == 1 ? Wkh : Wvh);

    const short* Ahb = Hh + (size_t)(mb * 128) * D_MODEL;
    const short* Alb = Hl + (size_t)(mb * 128) * D_MODEL;
    const short* Bhb = Wh + (size_t)nlocal * D_MODEL;

    fx4 acc[4][4];
#pragma unroll
    for (int i = 0; i < 4; ++i)
#pragma unroll
        for (int j = 0; j < 4; ++j) acc[i][j] = (fx4){0.f, 0.f, 0.f, 0.f};

    // stage tile kt (128 rows x 64 cols): 1024 chunks/array, 4/thread
    auto stage = [&](int kt) {
        int kb = kt * 64;
#pragma unroll
        for (int i = 0; i < 4; ++i) {
            int cd = i * 256 + t;
            int row = cd >> 3, p = cd & 7;
            int csw = (p ^ (row & 7)) << 3;
            size_t go = (size_t)row * D_MODEL + kb + csw;
            int dst = (i * 256 + w * 64) * 8;
            gl_lds16(Ahb + go, &Ah[dst]);
            gl_lds16(Bhb + go, &Bh[dst]);
            if (proj != 2) gl_lds16(Alb + go, &Al[dst]);
        }
    };
    // per-ks fragment reads keep register live-set small; order hi,lo per ks
    auto compute = [&]() {
#pragma unroll
        for (int ks = 0; ks < 2; ++ks) {
            sh8 afh[4], bfh[4];
#pragma unroll
            for (int mi = 0; mi < 4; ++mi) {
                int row = wr * 64 + mi * 16 + fr;
                afh[mi] = *(const sh8*)&Ah[row * 64 + ((((ks << 2) | g) ^ (row & 7)) << 3)];
            }
#pragma unroll
            for (int ni = 0; ni < 4; ++ni) {
                int row = wc * 64 + ni * 16 + fr;
                bfh[ni] = *(const sh8*)&Bh[row * 64 + ((((ks << 2) | g) ^ (row & 7)) << 3)];
            }
#pragma unroll
            for (int mi = 0; mi < 4; ++mi)
#pragma unroll
                for (int ni = 0; ni < 4; ++ni)
                    acc[mi][ni] = __builtin_amdgcn_mfma_f32_16x16x32_bf16(afh[mi], bfh[ni], acc[mi][ni], 0, 0, 0);
            if (proj != 2) {
                sh8 afl[4];
#pragma unroll
                for (int mi = 0; mi < 4; ++mi) {
                    int row = wr * 64 + mi * 16 + fr;
                    afl[mi] = *(const sh8*)&Al[row * 64 + ((((ks << 2) | g) ^ (row & 7)) << 3)];
                }
#pragma unroll
                for (int mi = 0; mi < 4; ++mi)
#pragma unroll
                    for (int ni = 0; ni < 4; ++ni)
                        acc[mi][ni] = __builtin_amdgcn_mfma_f32_16x16x32_bf16(afl[mi], bfh[ni], acc[mi][ni], 0, 0, 0);
            }
        }
    };

#pragma unroll 1
    for (int kt = 0; kt < 16; ++kt) {
        __syncthreads();
        stage(kt);
        __syncthreads();
        compute();
    }

#pragma unroll
    for (int mi = 0; mi < 4; ++mi)
#pragma unroll
        for (int ni = 0; ni < 4; ++ni)
#pragma unroll
            for (int r = 0; r < 4; ++r) {
                int m = mb * 128 + wr * 64 + mi * 16 + qrhi + r;
                int n = nb * 128 + wc * 64 + ni * 16 + fr;
                int nn = n & 1023;
                int h = nn >> 6, d = nn & 63;
                int b = m >> 11, s = m & 2047;
                size_t bh = (size_t)(b * NH + h);
                float val = acc[mi][ni][r];
                if (proj == 0) {
                    Qh[(bh * SEQ + s) * HD + d] = f2bf(val);
                } else if (proj == 1) {
                    Kh[(bh * SEQ + s) * HD + d] = f2bf(val);
                } else {
                    Vt[(bh * HD + d) * SEQ + s] = f2bf(val);
                }
            }
}

// swizzled LDS index (shorts): row-major [64][64], XOR bank swizzle
#define SW(row, scol) (((row) << 6) + ((scol) ^ (((row) & 7) << 3)))

// ---------------- flash attention v11: QK plain bf16, raw v_exp_f32 ----------
__global__ __launch_bounds__(256, 3) void attn_kernel(
    const short* __restrict__ Qhg, const short* __restrict__ Khg,
    const short* __restrict__ Vtg, const float* __restrict__ biasS,
    short* __restrict__ poB, float* __restrict__ plB) {
    __shared__ short Ks[64 * 64];
    __shared__ short Vs[64 * 64];
    __shared__ short Pl[4 * 16 * 72];
    __shared__ float Bt[192];

    int t = threadIdx.x;
    int lane = t & 63, w = t >> 6;
    int fr = lane & 15, g = lane >> 4;
    int fk = g << 3;
    int qrhi = g << 2;
    int qt = blockIdx.x, h = blockIdx.y;
    int b = blockIdx.z >> 1, half = blockIdx.z & 1;
    int qbase = qt * 128;
    int ktbase = half * 16;
    size_t bh = (size_t)(b * NH + h);

    sh8 qh[2][2];
#pragma unroll
    for (int qg = 0; qg < 2; ++qg)
#pragma unroll
        for (int ks = 0; ks < 2; ++ks) {
            int row = qbase + w * 32 + qg * 16 + fr;
            qh[qg][ks] = *(const sh8*)&Qhg[(bh * SEQ + row) * HD + ks * 32 + fk];
        }

    float lrow[2][4];
    fx4 o[2][4];
#pragma unroll
    for (int qg = 0; qg < 2; ++qg) {
#pragma unroll
        for (int r = 0; r < 4; ++r) lrow[qg][r] = 0.f;
#pragma unroll
        for (int di = 0; di < 4; ++di) o[qg][di] = (fx4){0.f, 0.f, 0.f, 0.f};
    }

    // hoisted kt-invariant LDS offsets
    int fo[2][4];
#pragma unroll
    for (int ks = 0; ks < 2; ++ks)
#pragma unroll
        for (int i = 0; i < 4; ++i) fo[ks][i] = SW(i * 16 + fr, ks * 32 + fk);
    int shftw = ((qrhi >> 3) & 1) << 3;
    int shftr = ((fr >> 3) & 1) << 3;
    int pbase = w * 1152;
    int pw = pbase + qrhi * 72 + fr + shftw;
    int pr0 = pbase + fr * 72 + fk + shftr;

    // glds staging: linear dest chunk cd; source chunk = p ^ (row&7)
    int sd[2], srow[2], schunk[2];
#pragma unroll
    for (int i = 0; i < 2; ++i) {
        int cd = i * 256 + t;
        int row = cd >> 3, p = cd & 7;
        sd[i] = cd * 8;
        srow[i] = row;
        schunk[i] = (p ^ (row & 7)) << 3;
    }

    const short* kbase = Khg + bh * SEQ * HD;
    const short* vbase = Vtg + bh * HD * SEQ;

    for (int ktl = 0; ktl < 16; ++ktl) {
        int kt = ktbase + ktl;
        __syncthreads();    // previous iteration's LDS reads complete
#pragma unroll
        for (int i = 0; i < 2; ++i) {
            gl_lds16(kbase + (size_t)(kt * 64 + srow[i]) * HD + schunk[i], &Ks[sd[i]]);
            gl_lds16(vbase + (size_t)srow[i] * SEQ + kt * 64 + schunk[i], &Vs[sd[i]]);
        }
        if (t < 191) Bt[t] = biasS[h * 4095 + 2047 + (kt * 64 - qbase - 127) + t];
        __syncthreads();    // glds + bias landed

        // QK^T (plain bf16: qh * kh)
        fx4 sc[2][4];
#pragma unroll
        for (int qg = 0; qg < 2; ++qg)
#pragma unroll
            for (int ni = 0; ni < 4; ++ni) sc[qg][ni] = (fx4){0.f, 0.f, 0.f, 0.f};
        __builtin_amdgcn_s_setprio(1);
#pragma unroll
        for (int ks = 0; ks < 2; ++ks)
#pragma unroll
            for (int ni = 0; ni < 4; ++ni) {
                sh8 kf = *(const sh8*)&Ks[fo[ks][ni]];
#pragma unroll
                for (int qg = 0; qg < 2; ++qg)
                    sc[qg][ni] = __builtin_amdgcn_mfma_f32_16x16x32_bf16(qh[qg][ks], kf, sc[qg][ni], 0, 0, 0);
            }
        __builtin_amdgcn_s_setprio(0);

        // per-qg: softmax -> P -> PV
#pragma unroll
        for (int qg = 0; qg < 2; ++qg) {
#pragma unroll
            for (int r = 0; r < 4; ++r) {
                int bidx0 = 127 + fr - (w * 32 + qg * 16 + qrhi + r);
                float psum = 0.f;
#pragma unroll
                for (int ni = 0; ni < 4; ++ni) {
                    float p = fexp2(fmaf(sc[qg][ni][r], LOG2E, Bt[bidx0 + ni * 16]));
                    sc[qg][ni][r] = p;
                    psum += p;
                }
                lrow[qg][r] += psum;
#pragma unroll
                for (int ni = 0; ni < 4; ++ni)
                    Pl[pw + r * 72 + ni * 16] = truncbf(sc[qg][ni][r]);
            }
            sh8 pa0 = *(const sh8*)&Pl[pr0];
            sh8 pa1 = *(const sh8*)&Pl[pr0 + 32];
            __builtin_amdgcn_s_setprio(1);
#pragma unroll
            for (int di = 0; di < 4; ++di) {
                sh8 vb0 = *(const sh8*)&Vs[fo[0][di]];
                sh8 vb1 = *(const sh8*)&Vs[fo[1][di]];
                o[qg][di] = __builtin_amdgcn_mfma_f32_16x16x32_bf16(pa0, vb0, o[qg][di], 0, 0, 0);
                o[qg][di] = __builtin_amdgcn_mfma_f32_16x16x32_bf16(pa1, vb1, o[qg][di], 0, 0, 0);
            }
            __builtin_amdgcn_s_setprio(0);
        }
    }

#pragma unroll
    for (int qg = 0; qg < 2; ++qg)
#pragma unroll
        for (int r = 0; r < 4; ++r) {
#pragma unroll
            for (int off = 1; off < 16; off <<= 1)
                lrow[qg][r] += __shfl_xor(lrow[qg][r], off, 64);
        }

    // epilogue: normalized partial O (bf16) + partial l (f32)
    short* po = poB + (size_t)half * (NB * SEQ * (size_t)D_MODEL);
    float* pl = plB + (size_t)half * (NB * NH * SEQ);
#pragma unroll
    for (int qg = 0; qg < 2; ++qg)
#pragma unroll
        for (int di = 0; di < 4; ++di)
#pragma unroll
            for (int r = 0; r < 4; ++r) {
                int q = qbase + w * 32 + qg * 16 + qrhi + r;
                int d = di * 16 + fr;
                po[((size_t)b * SEQ + q) * D_MODEL + h * HD + d] =
                    f2bf(o[qg][di][r] / lrow[qg][r]);
            }
    if (fr == 0) {
#pragma unroll
        for (int qg = 0; qg < 2; ++qg)
#pragma unroll
            for (int r = 0; r < 4; ++r) {
                int q = qbase + w * 32 + qg * 16 + qrhi + r;
                pl[bh * SEQ + q] = lrow[qg][r];
            }
    }
}

// ---------------- combine: ctx = (l0*O0' + l1*O1') / (l0+l1), bf16 -----------
__global__ __launch_bounds__(256) void combine_kernel(
    const short* __restrict__ poB, const float* __restrict__ plB,
    short* __restrict__ ctx) {
    const size_t NEl = (size_t)NB * SEQ * D_MODEL;
    int idx = blockIdx.x * 256 + threadIdx.x;
    if (idx >= (int)(NEl / 8)) return;
    size_t e = (size_t)idx * 8;
    int c = (int)(e & 1023);
    int h = c >> 6;
    int bq = (int)(e >> 10);
    int b = bq >> 11, q = bq & 2047;
    sh8 a0 = *(const sh8*)&poB[e];
    sh8 a1 = *(const sh8*)&poB[NEl + e];
    int li = (b * NH + h) * SEQ + q;
    float l0 = plB[li];
    float l1 = plB[NB * NH * SEQ + li];
    float inv = 1.0f / (l0 + l1);
    float w0 = l0 * inv, w1 = l1 * inv;
    sh8 r;
#pragma unroll
    for (int j = 0; j < 8; ++j)
        r[j] = f2bf(bf2f(a0[j]) * w0 + bf2f(a1[j]) * w1);
    *(sh8*)&ctx[e] = r;
}

// ---------------- output projection: 64x128 tile, dbuf, gload_lds ------------
__global__ __launch_bounds__(256) void o_gemm(
    const short* __restrict__ Actx, const short* __restrict__ Woh,
    float* __restrict__ out) {
    __shared__ short Ab[2][2048];
    __shared__ short Bb[2][4096];

    int t = threadIdx.x;
    int lane = t & 63, w = t >> 6;
    int wr = w >> 1, wc = w & 1;
    int fr = lane & 15, g = lane >> 4;
    int qrhi = g << 2;

    int lin = blockIdx.y * 8 + blockIdx.x;      // 512 blocks
    int swz = (lin & 7) * 64 + (lin >> 3);
    int nb = swz & 7, mb = swz >> 3;

    fx4 acc[2][4];
#pragma unroll
    for (int i = 0; i < 2; ++i)
#pragma unroll
        for (int j = 0; j < 4; ++j) acc[i][j] = (fx4){0.f, 0.f, 0.f, 0.f};

    int row0 = t >> 2, c0 = t & 3;

    auto stage = [&](int kt, int buf) {
        int kb = kt * 32;
        {
            int row = row0;
            int csw = (c0 ^ (row & 3)) << 3;
            gl_lds16(&Actx[(size_t)(mb * 64 + row) * D_MODEL + kb + csw],
                     &Ab[buf][(w * 64) * 8]);
        }
#pragma unroll
        for (int i = 0; i < 2; ++i) {
            int row = row0 + i * 64;
            int csw = (c0 ^ (row & 3)) << 3;
            gl_lds16(&Woh[(size_t)(nb * 128 + row) * D_MODEL + kb + csw],
                     &Bb[buf][(i * 256 + w * 64) * 8]);
        }
    };
    auto compute = [&](int buf) {
        sh8 af[2], bf[4];
#pragma unroll
        for (int mi = 0; mi < 2; ++mi) {
            int row = wr * 32 + mi * 16 + fr;
            af[mi] = *(const sh8*)&Ab[buf][(row << 5) + ((g ^ (row & 3)) << 3)];
        }
#pragma unroll
        for (int ni = 0; ni < 4; ++ni) {
            int row = wc * 64 + ni * 16 + fr;
            bf[ni] = *(const sh8*)&Bb[buf][(row << 5) + ((g ^ (row & 3)) << 3)];
        }
#pragma unroll
        for (int mi = 0; mi < 2; ++mi)
#pragma unroll
            for (int ni = 0; ni < 4; ++ni)
                acc[mi][ni] = __builtin_amdgcn_mfma_f32_16x16x32_bf16(af[mi], bf[ni], acc[mi][ni], 0, 0, 0);
    };

    stage(0, 0);
    asm volatile("s_waitcnt vmcnt(0)" ::: "memory");
    __builtin_amdgcn_s_barrier();

    int cur = 0;
#pragma unroll 1
    for (int kt = 0; kt < 31; ++kt) {
        stage(kt + 1, cur ^ 1);
        compute(cur);
        asm volatile("s_waitcnt vmcnt(0)" ::: "memory");
        __builtin_amdgcn_s_barrier();
        cur ^= 1;
    }
    compute(cur);

#pragma unroll
    for (int mi = 0; mi < 2; ++mi)
#pragma unroll
        for (int ni = 0; ni < 4; ++ni)
#pragma unroll
            for (int r = 0; r < 4; ++r) {
                int m = mb * 64 + wr * 32 + mi * 16 + qrhi + r;
                int n = nb * 128 + wc * 64 + ni * 16 + fr;
                out[(size_t)m * D_MODEL + n] = acc[mi][ni][r];
            }
}

extern "C" void kernel_launch(void* const* d_in, const int* in_sizes, int n_in,
                              void* d_out, int out_size, void* d_ws, size_t ws_size,
                              hipStream_t stream) {
    const float* hidden = (const float*)d_in[0];
    const float* Wq = (const float*)d_in[1];
    const float* Wk = (const float*)d_in[2];
    const float* Wv = (const float*)d_in[3];
    const float* Wo = (const float*)d_in[4];
    const float* rel = (const float*)d_in[5];
    float* out = (float*)d_out;

    const size_t NE = (size_t)NB * NH * SEQ * HD;   // 4,194,304 (x2B = 8MB)
    const size_t WE = (size_t)D_MODEL * D_MODEL;    // 1,048,576 (x2B = 2MB)
    char* ws = (char*)d_ws;
    short* Qh = (short*)(ws + 0 * NE * 2);
    short* Kh = (short*)(ws + 2 * NE * 2);
    short* Vt = (short*)(ws + 4 * NE * 2);          // [32,40)MB; dead after attn
    char* wsp = ws + 5 * NE * 2;                    // 40MB mark
    short* Wqh = (short*)(wsp + 0 * WE * 2);
    short* Wkh = (short*)(wsp + 2 * WE * 2);
    short* Wvh = (short*)(wsp + 4 * WE * 2);
    short* Woh = (short*)(wsp + 6 * WE * 2);        // survives until o_gemm
    float* bias = (float*)(wsp + 7 * WE * 2);       // 54MB mark, 256KB
    float* plB = (float*)(wsp + 7 * WE * 2 + 262144);  // 512KB partial l
    short* ctxb = Vt;   // alias: Vt dead after attn; combine writes here

    // Hh/Hl then partial-O both live in d_out (16MB), phase-disjoint.
    short* Hh = (short*)d_out;
    short* Hl = Hh + NE;
    short* poB = (short*)d_out;

    bias_kernel<<<dim3(256), dim3(256), 0, stream>>>(rel, bias);
    presplit_h_cvt_w<<<dim3(8192), dim3(256), 0, stream>>>(
        hidden, Wq, Wk, Wv, Wo, Hh, Hl, Wqh, Wkh, Wvh, Woh);
    qkv_gemm<<<dim3(24, 32), dim3(256), 0, stream>>>(
        Hh, Hl, Wqh, Wkh, Wvh, Qh, Kh, Vt);
    attn_kernel<<<dim3(16, 16, 4), dim3(256), 0, stream>>>(
        Qh, Kh, Vt, bias, poB, plB);
    combine_kernel<<<dim3(2048), dim3(256), 0, stream>>>(poB, plB, ctxb);
    o_gemm<<<dim3(8, 64), dim3(256), 0, stream>>>(ctxb, Woh, out);
}